// Round 1
// baseline (2039.728 us; speedup 1.0000x reference)
//
#include <hip/hip_runtime.h>
#include <hip/hip_bf16.h>
#include <math.h>

// Problem constants
#define BB 8
#define CC 256
#define HH 64
#define WW 64
#define GG 16
#define GCH 16
#define PP 9
#define NPIX (BB*HH*WW)   // 32768

// ---------------------------------------------------------------------------
// K1: 5x5 depthwise conv, pad 2. x: NCHW fp32 -> out: NHWC fp32
// one thread per output element, channel-fastest (coalesced NHWC writes)
__global__ void conv0_kernel(const float* __restrict__ x, const float* __restrict__ w,
                             const float* __restrict__ b, float* __restrict__ out) {
    int idx = blockIdx.x * blockDim.x + threadIdx.x;       // ((n*H+h)*W+w)*C + c
    int c = idx & 255;
    int pix = idx >> 8;
    int wo = pix & 63;
    int ho = (pix >> 6) & 63;
    int n  = pix >> 12;
    const float* xp = x + ((size_t)(n*CC + c))*HH*WW;
    const float* wp = w + c*25;
    float acc = b[c];
    #pragma unroll
    for (int dy = 0; dy < 5; ++dy) {
        int yy = ho + dy - 2;
        if (yy < 0 || yy >= HH) continue;
        #pragma unroll
        for (int dx = 0; dx < 5; ++dx) {
            int xx = wo + dx - 2;
            if (xx < 0 || xx >= WW) continue;
            acc += xp[yy*WW + xx] * wp[dy*5 + dx];
        }
    }
    out[idx] = acc;
}

// ---------------------------------------------------------------------------
// K2: 3x3 depthwise conv on NHWC + LayerNorm(C) + exact GELU -> x1 NHWC
// one block per pixel, 256 threads = channels
__global__ void dwln_kernel(const float* __restrict__ inp, const float* __restrict__ dww,
                            const float* __restrict__ dwb, const float* __restrict__ lng,
                            const float* __restrict__ lnb, float* __restrict__ x1) {
    int pix = blockIdx.x;
    int c = threadIdx.x;
    int wo = pix & 63;
    int ho = (pix >> 6) & 63;
    int n  = pix >> 12;
    float acc = dwb[c];
    #pragma unroll
    for (int dy = 0; dy < 3; ++dy) {
        int yy = ho + dy - 1;
        if (yy < 0 || yy >= HH) continue;
        #pragma unroll
        for (int dx = 0; dx < 3; ++dx) {
            int xx = wo + dx - 1;
            if (xx < 0 || xx >= WW) continue;
            acc += inp[(((size_t)(n*HH + yy))*WW + xx)*CC + c] * dww[c*9 + dy*3 + dx];
        }
    }
    // LayerNorm over the 256 channels of this block
    __shared__ float ls[8];
    float s1 = acc, s2 = acc*acc;
    #pragma unroll
    for (int o = 1; o < 64; o <<= 1) {
        s1 += __shfl_xor(s1, o);
        s2 += __shfl_xor(s2, o);
    }
    int wid = threadIdx.x >> 6, lane = threadIdx.x & 63;
    if (lane == 0) { ls[wid] = s1; ls[4 + wid] = s2; }
    __syncthreads();
    float t1 = ls[0] + ls[1] + ls[2] + ls[3];
    float t2 = ls[4] + ls[5] + ls[6] + ls[7];
    float mu  = t1 * (1.0f/256.0f);
    float var = t2 * (1.0f/256.0f) - mu*mu;
    float r = rsqrtf(var + 1e-5f);
    float v = (acc - mu) * r * lng[c] + lnb[c];
    // exact GELU: 0.5*v*(1+erf(v/sqrt(2)))
    float g = 0.5f * v * (1.0f + erff(v * 0.70710678118654752440f));
    x1[(size_t)pix*CC + c] = g;
}

// ---------------------------------------------------------------------------
// K3: generic fp32 GEMM  C[M,N] = A[M,K] @ B + bias
// TRANSB==0: B is [K,N] row-major.  TRANSB==1: B is [N,K] row-major (use B^T).
// 64x64 tile per block of 256 threads, 4x4 micro-tile per thread, BK=16.
template <int TRANSB>
__global__ void gemm_kernel(const float* __restrict__ A, const float* __restrict__ Bw,
                            const float* __restrict__ bias, float* __restrict__ Cc,
                            int M, int N, int K) {
    __shared__ float As[16][65];
    __shared__ float Bs[16][65];
    int bm = blockIdx.y * 64;
    int bn = blockIdx.x * 64;
    int tid = threadIdx.x;
    float acc[4][4] = {};
    for (int k0 = 0; k0 < K; k0 += 16) {
        #pragma unroll
        for (int i = 0; i < 4; ++i) {
            int t = tid + i*256;          // 0..1023
            int m = t & 63, kk = t >> 6;
            As[kk][m] = A[(size_t)(bm + m)*K + k0 + kk];
        }
        #pragma unroll
        for (int i = 0; i < 4; ++i) {
            int t = tid + i*256;
            int nn = t & 63, kk = t >> 6;
            int gn = bn + nn;
            float v = 0.0f;
            if (gn < N) {
                if (TRANSB) v = Bw[(size_t)gn*K + k0 + kk];
                else        v = Bw[(size_t)(k0 + kk)*N + gn];
            }
            Bs[kk][nn] = v;
        }
        __syncthreads();
        int tx = tid & 15, ty = tid >> 4;
        #pragma unroll
        for (int kk = 0; kk < 16; ++kk) {
            float a[4], b[4];
            #pragma unroll
            for (int i = 0; i < 4; ++i) a[i] = As[kk][ty*4 + i];
            #pragma unroll
            for (int j = 0; j < 4; ++j) b[j] = Bs[kk][tx*4 + j];
            #pragma unroll
            for (int i = 0; i < 4; ++i)
                #pragma unroll
                for (int j = 0; j < 4; ++j)
                    acc[i][j] += a[i] * b[j];
        }
        __syncthreads();
    }
    int tx = tid & 15, ty = tid >> 4;
    #pragma unroll
    for (int i = 0; i < 4; ++i) {
        int m = bm + ty*4 + i;
        #pragma unroll
        for (int j = 0; j < 4; ++j) {
            int n = bn + tx*4 + j;
            if (n < N) Cc[(size_t)m*N + n] = acc[i][j] + bias[n];
        }
    }
}

// ---------------------------------------------------------------------------
// K4: in-place softmax over P=9 per (pixel, group)
__global__ void softmax_kernel(float* __restrict__ m) {
    int idx = blockIdx.x * blockDim.x + threadIdx.x;  // pix*16+g, total 524288
    float* p = m + (size_t)idx * 9;
    float v[9];
    float mx = -1e30f;
    #pragma unroll
    for (int i = 0; i < 9; ++i) { v[i] = p[i]; mx = fmaxf(mx, v[i]); }
    float s = 0.0f;
    #pragma unroll
    for (int i = 0; i < 9; ++i) { v[i] = expf(v[i] - mx); s += v[i]; }
    float r = 1.0f / s;
    #pragma unroll
    for (int i = 0; i < 9; ++i) p[i] = v[i] * r;
}

// ---------------------------------------------------------------------------
// K5: DCNv3 core. xproj NHWC, offset (pix,288), mask (pix,144) -> y NHWC
// one block per pixel, thread per channel
__global__ void dcn_kernel(const float* __restrict__ xproj, const float* __restrict__ off,
                           const float* __restrict__ msk, float* __restrict__ y) {
    int pix = blockIdx.x;
    int c = threadIdx.x;
    int g = c >> 4;
    int wo = pix & 63;
    int ho = (pix >> 6) & 63;
    int n  = pix >> 12;
    const float* ob = off + (size_t)pix*288 + g*18;
    const float* mb = msk + (size_t)pix*144 + g*9;
    const float* xb = xproj + (size_t)n*HH*WW*CC + c;
    float acc = 0.0f;
    #pragma unroll
    for (int p = 0; p < 9; ++p) {
        float offx = ob[p*2 + 0];
        float offy = ob[p*2 + 1];
        float mval = mb[p];
        int dx = (p / 3) - 1;   // kw-major: gx = repeat(pts,3)
        int dy = (p % 3) - 1;   // gy = tile(pts,3)
        float fx = (float)(wo + dx) + offx;   // unpadded coords
        float fy = (float)(ho + dy) + offy;
        float x0f = floorf(fx), y0f = floorf(fy);
        int x0 = (int)x0f, y0 = (int)y0f;
        float wx1 = fx - x0f, wx0 = 1.0f - wx1;
        float wy1 = fy - y0f, wy0 = 1.0f - wy1;
        int x1i = x0 + 1, y1i = y0 + 1;
        float v00 = (y0  >= 0 && y0  < HH && x0  >= 0 && x0  < WW) ? xb[((size_t)y0 *WW + x0 )*CC] : 0.0f;
        float v01 = (y0  >= 0 && y0  < HH && x1i >= 0 && x1i < WW) ? xb[((size_t)y0 *WW + x1i)*CC] : 0.0f;
        float v10 = (y1i >= 0 && y1i < HH && x0  >= 0 && x0  < WW) ? xb[((size_t)y1i*WW + x0 )*CC] : 0.0f;
        float v11 = (y1i >= 0 && y1i < HH && x1i >= 0 && x1i < WW) ? xb[((size_t)y1i*WW + x1i)*CC] : 0.0f;
        acc += mval * (wy0*(wx0*v00 + wx1*v01) + wy1*(wx0*v10 + wx1*v11));
    }
    y[(size_t)pix*CC + c] = acc;
}

// ---------------------------------------------------------------------------
// K6: out[n,d,h,w] = x[n,d,h,w] * attn[pix, d]   (16x16 LDS transpose tile)
__global__ void finmul_kernel(const float* __restrict__ x, const float* __restrict__ attn,
                              float* __restrict__ out) {
    __shared__ float t[16][17];
    int pix0 = blockIdx.x * 16;
    int d0   = blockIdx.y * 16;
    int li = threadIdx.x & 15;
    int lj = threadIdx.x >> 4;
    t[lj][li] = attn[(size_t)(pix0 + lj)*CC + d0 + li];
    __syncthreads();
    int pix = pix0 + li;
    int wo = pix & 63;
    int ho = (pix >> 6) & 63;
    int n  = pix >> 12;
    int d = d0 + lj;
    size_t oidx = (((size_t)n*CC + d)*HH + ho)*WW + wo;
    out[oidx] = x[oidx] * t[li][lj];
}

// ---------------------------------------------------------------------------
extern "C" void kernel_launch(void* const* d_in, const int* in_sizes, int n_in,
                              void* d_out, int out_size, void* d_ws, size_t ws_size,
                              hipStream_t stream) {
    const float* x      = (const float*)d_in[0];
    const float* conv0w = (const float*)d_in[1];
    const float* conv0b = (const float*)d_in[2];
    const float* dww    = (const float*)d_in[3];
    const float* dwb    = (const float*)d_in[4];
    const float* lng    = (const float*)d_in[5];
    const float* lnb    = (const float*)d_in[6];
    const float* offw   = (const float*)d_in[7];
    const float* offb   = (const float*)d_in[8];
    const float* mskw   = (const float*)d_in[9];
    const float* mskb   = (const float*)d_in[10];
    const float* inw    = (const float*)d_in[11];
    const float* inb    = (const float*)d_in[12];
    const float* outpw  = (const float*)d_in[13];
    const float* outpb  = (const float*)d_in[14];
    const float* pww    = (const float*)d_in[15];
    const float* pwb    = (const float*)d_in[16];

    float* ws = (float*)d_ws;
    float* inp  = ws;                 // 8,388,608 floats (NPIX*256)
    float* x1   = ws + 8388608;       // 8,388,608
    float* xpj  = ws + 16777216;      // 8,388,608
    float* off  = ws + 25165824;      // 9,437,184 (NPIX*288)
    float* msk  = ws + 34603008;      // 4,718,592 (NPIX*144)
    float* y    = inp;                // reuse (inp dead after in_proj gemm)
    float* z    = x1;                 // reuse (x1 dead after off/msk gemms)
    float* attn = xpj;                // reuse (xproj dead after dcn)
    float* out  = (float*)d_out;

    // 1. conv0 5x5 dw: x NCHW -> inp NHWC
    conv0_kernel<<<NPIX, 256, 0, stream>>>(x, conv0w, conv0b, inp);
    // 2. dw3x3 + LN + GELU -> x1
    dwln_kernel<<<NPIX, 256, 0, stream>>>(inp, dww, dwb, lng, lnb, x1);
    // 3. xproj = inp @ in_w + in_b
    gemm_kernel<0><<<dim3(4, NPIX/64), 256, 0, stream>>>(inp, inw, inb, xpj, NPIX, 256, 256);
    // 4. offset = x1 @ off_w + off_b
    gemm_kernel<0><<<dim3(5, NPIX/64), 256, 0, stream>>>(x1, offw, offb, off, NPIX, 288, 256);
    // 5. mask logits = x1 @ msk_w + msk_b
    gemm_kernel<0><<<dim3(3, NPIX/64), 256, 0, stream>>>(x1, mskw, mskb, msk, NPIX, 144, 256);
    // 6. softmax over P per (pix, g)
    softmax_kernel<<<(NPIX*GG)/256, 256, 0, stream>>>(msk);
    // 7. DCN core -> y
    dcn_kernel<<<NPIX, 256, 0, stream>>>(xpj, off, msk, y);
    // 8. z = y @ outp_w + outp_b
    gemm_kernel<0><<<dim3(4, NPIX/64), 256, 0, stream>>>(y, outpw, outpb, z, NPIX, 256, 256);
    // 9. attn = z @ pw_w^T + pw_b
    gemm_kernel<1><<<dim3(4, NPIX/64), 256, 0, stream>>>(z, pww, pwb, attn, NPIX, 256, 256);
    // 10. out = x * attn (NCHW)
    finmul_kernel<<<dim3(NPIX/16, 16), 256, 0, stream>>>(x, attn, out);
}

// Round 2
// 932.865 us; speedup vs baseline: 2.1865x; 2.1865x over previous
//
#include <hip/hip_runtime.h>
#include <hip/hip_bf16.h>
#include <math.h>

// Problem constants
#define BB 8
#define CC 256
#define HH 64
#define WW 64
#define GG 16
#define GCH 16
#define PP 9
#define NPIX (BB*HH*WW)   // 32768

// ---------------------------------------------------------------------------
// K1 v2: 5x5 depthwise conv, pad 2. x: NCHW fp32 -> out: NHWC fp32
// Block = 256 threads = 16 channels x 16 lanes-of-pixels; tile = 16x16 pixels.
// Halo (16ch x 20x20) staged in LDS with row-contiguous global reads.
// Writes: lane-fastest channel index -> 64B contiguous segments.
#define C0TILE 16
#define C0PLANE 421   // 20 rows * 21 (padded) + 1 -> odd stride, <=2-way banks
__global__ void conv0_kernel(const float* __restrict__ x, const float* __restrict__ w,
                             const float* __restrict__ b, float* __restrict__ out) {
    __shared__ float sx[16 * C0PLANE];   // 26944 B
    int t  = threadIdx.x;
    int tx = blockIdx.x & 3;             // 4 tiles across W
    int ty = blockIdx.x >> 2;            // 4 tiles across H
    int cg = blockIdx.y;                 // channel group (16 channels)
    int n  = blockIdx.z;
    int h0 = ty * 16, w0 = tx * 16;
    int c0 = cg * 16;

    // Load halo: 320 (c,row) pairs, 20 floats each, row-contiguous reads.
    {
        int pair = t;                    // pass 1: pairs 0..255
        #pragma unroll
        for (int pass = 0; pass < 2; ++pass) {
            if (pair < 320) {
                int c   = pair / 20;
                int row = pair - c * 20;
                int gy  = h0 - 2 + row;
                const float* src = x + (((size_t)(n * CC + c0 + c)) * HH + gy) * WW;
                float* dst = &sx[c * C0PLANE + row * 21];
                bool yok = (gy >= 0) & (gy < HH);
                #pragma unroll
                for (int j = 0; j < 20; ++j) {
                    int gx = w0 - 2 + j;
                    dst[j] = (yok && gx >= 0 && gx < WW) ? src[gx] : 0.0f;
                }
            }
            pair = 256 + t;              // pass 2: pairs 256..319 (t<64)
        }
    }
    __syncthreads();

    int c = t & 15;
    float wreg[25];
    const float* wp = w + (c0 + c) * 25;
    #pragma unroll
    for (int i = 0; i < 25; ++i) wreg[i] = wp[i];
    float bias = b[c0 + c];
    const float* cp = &sx[c * C0PLANE];

    #pragma unroll
    for (int it = 0; it < 16; ++it) {
        int q  = (t >> 4) + it * 16;     // pixel-in-tile 0..255
        int ph = q >> 4, pw = q & 15;
        float acc = bias;
        #pragma unroll
        for (int dy = 0; dy < 5; ++dy)
            #pragma unroll
            for (int dx = 0; dx < 5; ++dx)
                acc += cp[(ph + dy) * 21 + (pw + dx)] * wreg[dy * 5 + dx];
        size_t pix = (size_t)n * 4096 + (h0 + ph) * 64 + (w0 + pw);
        out[(pix << 8) + c0 + c] = acc;
    }
}

// ---------------------------------------------------------------------------
// K2: 3x3 depthwise conv on NHWC + LayerNorm(C) + exact GELU -> x1 NHWC
// one block per pixel, 256 threads = channels
__global__ void dwln_kernel(const float* __restrict__ inp, const float* __restrict__ dww,
                            const float* __restrict__ dwb, const float* __restrict__ lng,
                            const float* __restrict__ lnb, float* __restrict__ x1) {
    int pix = blockIdx.x;
    int c = threadIdx.x;
    int wo = pix & 63;
    int ho = (pix >> 6) & 63;
    int n  = pix >> 12;
    float acc = dwb[c];
    #pragma unroll
    for (int dy = 0; dy < 3; ++dy) {
        int yy = ho + dy - 1;
        if (yy < 0 || yy >= HH) continue;
        #pragma unroll
        for (int dx = 0; dx < 3; ++dx) {
            int xx = wo + dx - 1;
            if (xx < 0 || xx >= WW) continue;
            acc += inp[(((size_t)(n*HH + yy))*WW + xx)*CC + c] * dww[c*9 + dy*3 + dx];
        }
    }
    // LayerNorm over the 256 channels of this block
    __shared__ float ls[8];
    float s1 = acc, s2 = acc*acc;
    #pragma unroll
    for (int o = 1; o < 64; o <<= 1) {
        s1 += __shfl_xor(s1, o);
        s2 += __shfl_xor(s2, o);
    }
    int wid = threadIdx.x >> 6, lane = threadIdx.x & 63;
    if (lane == 0) { ls[wid] = s1; ls[4 + wid] = s2; }
    __syncthreads();
    float t1 = ls[0] + ls[1] + ls[2] + ls[3];
    float t2 = ls[4] + ls[5] + ls[6] + ls[7];
    float mu  = t1 * (1.0f/256.0f);
    float var = t2 * (1.0f/256.0f) - mu*mu;
    float r = rsqrtf(var + 1e-5f);
    float v = (acc - mu) * r * lng[c] + lnb[c];
    // exact GELU: 0.5*v*(1+erf(v/sqrt(2)))
    float g = 0.5f * v * (1.0f + erff(v * 0.70710678118654752440f));
    x1[(size_t)pix*CC + c] = g;
}

// ---------------------------------------------------------------------------
// K3: generic fp32 GEMM  C[M,N] = A[M,K] @ B + bias
// TRANSB==0: B is [K,N] row-major.  TRANSB==1: B is [N,K] row-major (use B^T).
// 64x64 tile per block of 256 threads, 4x4 micro-tile per thread, BK=16.
template <int TRANSB>
__global__ void gemm_kernel(const float* __restrict__ A, const float* __restrict__ Bw,
                            const float* __restrict__ bias, float* __restrict__ Cc,
                            int M, int N, int K) {
    __shared__ float As[16][65];
    __shared__ float Bs[16][65];
    int bm = blockIdx.y * 64;
    int bn = blockIdx.x * 64;
    int tid = threadIdx.x;
    float acc[4][4] = {};
    for (int k0 = 0; k0 < K; k0 += 16) {
        #pragma unroll
        for (int i = 0; i < 4; ++i) {
            int t = tid + i*256;          // 0..1023
            int m = t & 63, kk = t >> 6;
            As[kk][m] = A[(size_t)(bm + m)*K + k0 + kk];
        }
        #pragma unroll
        for (int i = 0; i < 4; ++i) {
            int t = tid + i*256;
            int nn = t & 63, kk = t >> 6;
            int gn = bn + nn;
            float v = 0.0f;
            if (gn < N) {
                if (TRANSB) v = Bw[(size_t)gn*K + k0 + kk];
                else        v = Bw[(size_t)(k0 + kk)*N + gn];
            }
            Bs[kk][nn] = v;
        }
        __syncthreads();
        int tx = tid & 15, ty = tid >> 4;
        #pragma unroll
        for (int kk = 0; kk < 16; ++kk) {
            float a[4], b[4];
            #pragma unroll
            for (int i = 0; i < 4; ++i) a[i] = As[kk][ty*4 + i];
            #pragma unroll
            for (int j = 0; j < 4; ++j) b[j] = Bs[kk][tx*4 + j];
            #pragma unroll
            for (int i = 0; i < 4; ++i)
                #pragma unroll
                for (int j = 0; j < 4; ++j)
                    acc[i][j] += a[i] * b[j];
        }
        __syncthreads();
    }
    int tx = tid & 15, ty = tid >> 4;
    #pragma unroll
    for (int i = 0; i < 4; ++i) {
        int m = bm + ty*4 + i;
        #pragma unroll
        for (int j = 0; j < 4; ++j) {
            int n = bn + tx*4 + j;
            if (n < N) Cc[(size_t)m*N + n] = acc[i][j] + bias[n];
        }
    }
}

// ---------------------------------------------------------------------------
// K4: in-place softmax over P=9 per (pixel, group)
__global__ void softmax_kernel(float* __restrict__ m) {
    int idx = blockIdx.x * blockDim.x + threadIdx.x;  // pix*16+g, total 524288
    float* p = m + (size_t)idx * 9;
    float v[9];
    float mx = -1e30f;
    #pragma unroll
    for (int i = 0; i < 9; ++i) { v[i] = p[i]; mx = fmaxf(mx, v[i]); }
    float s = 0.0f;
    #pragma unroll
    for (int i = 0; i < 9; ++i) { v[i] = expf(v[i] - mx); s += v[i]; }
    float r = 1.0f / s;
    #pragma unroll
    for (int i = 0; i < 9; ++i) p[i] = v[i] * r;
}

// ---------------------------------------------------------------------------
// K5: DCNv3 core. xproj NHWC, offset (pix,288), mask (pix,144) -> y NHWC
// one block per pixel, thread per channel
__global__ void dcn_kernel(const float* __restrict__ xproj, const float* __restrict__ off,
                           const float* __restrict__ msk, float* __restrict__ y) {
    int pix = blockIdx.x;
    int c = threadIdx.x;
    int g = c >> 4;
    int wo = pix & 63;
    int ho = (pix >> 6) & 63;
    int n  = pix >> 12;
    const float* ob = off + (size_t)pix*288 + g*18;
    const float* mb = msk + (size_t)pix*144 + g*9;
    const float* xb = xproj + (size_t)n*HH*WW*CC + c;
    float acc = 0.0f;
    #pragma unroll
    for (int p = 0; p < 9; ++p) {
        float offx = ob[p*2 + 0];
        float offy = ob[p*2 + 1];
        float mval = mb[p];
        int dx = (p / 3) - 1;   // kw-major: gx = repeat(pts,3)
        int dy = (p % 3) - 1;   // gy = tile(pts,3)
        float fx = (float)(wo + dx) + offx;   // unpadded coords
        float fy = (float)(ho + dy) + offy;
        float x0f = floorf(fx), y0f = floorf(fy);
        int x0 = (int)x0f, y0 = (int)y0f;
        float wx1 = fx - x0f, wx0 = 1.0f - wx1;
        float wy1 = fy - y0f, wy0 = 1.0f - wy1;
        int x1i = x0 + 1, y1i = y0 + 1;
        float v00 = (y0  >= 0 && y0  < HH && x0  >= 0 && x0  < WW) ? xb[((size_t)y0 *WW + x0 )*CC] : 0.0f;
        float v01 = (y0  >= 0 && y0  < HH && x1i >= 0 && x1i < WW) ? xb[((size_t)y0 *WW + x1i)*CC] : 0.0f;
        float v10 = (y1i >= 0 && y1i < HH && x0  >= 0 && x0  < WW) ? xb[((size_t)y1i*WW + x0 )*CC] : 0.0f;
        float v11 = (y1i >= 0 && y1i < HH && x1i >= 0 && x1i < WW) ? xb[((size_t)y1i*WW + x1i)*CC] : 0.0f;
        acc += mval * (wy0*(wx0*v00 + wx1*v01) + wy1*(wx0*v10 + wx1*v11));
    }
    y[(size_t)pix*CC + c] = acc;
}

// ---------------------------------------------------------------------------
// K6: out[n,d,h,w] = x[n,d,h,w] * attn[pix, d]   (16x16 LDS transpose tile)
__global__ void finmul_kernel(const float* __restrict__ x, const float* __restrict__ attn,
                              float* __restrict__ out) {
    __shared__ float t[16][17];
    int pix0 = blockIdx.x * 16;
    int d0   = blockIdx.y * 16;
    int li = threadIdx.x & 15;
    int lj = threadIdx.x >> 4;
    t[lj][li] = attn[(size_t)(pix0 + lj)*CC + d0 + li];
    __syncthreads();
    int pix = pix0 + li;
    int wo = pix & 63;
    int ho = (pix >> 6) & 63;
    int n  = pix >> 12;
    int d = d0 + lj;
    size_t oidx = (((size_t)n*CC + d)*HH + ho)*WW + wo;
    out[oidx] = x[oidx] * t[li][lj];
}

// ---------------------------------------------------------------------------
extern "C" void kernel_launch(void* const* d_in, const int* in_sizes, int n_in,
                              void* d_out, int out_size, void* d_ws, size_t ws_size,
                              hipStream_t stream) {
    const float* x      = (const float*)d_in[0];
    const float* conv0w = (const float*)d_in[1];
    const float* conv0b = (const float*)d_in[2];
    const float* dww    = (const float*)d_in[3];
    const float* dwb    = (const float*)d_in[4];
    const float* lng    = (const float*)d_in[5];
    const float* lnb    = (const float*)d_in[6];
    const float* offw   = (const float*)d_in[7];
    const float* offb   = (const float*)d_in[8];
    const float* mskw   = (const float*)d_in[9];
    const float* mskb   = (const float*)d_in[10];
    const float* inw    = (const float*)d_in[11];
    const float* inb    = (const float*)d_in[12];
    const float* outpw  = (const float*)d_in[13];
    const float* outpb  = (const float*)d_in[14];
    const float* pww    = (const float*)d_in[15];
    const float* pwb    = (const float*)d_in[16];

    float* ws = (float*)d_ws;
    float* inp  = ws;                 // 8,388,608 floats (NPIX*256)
    float* x1   = ws + 8388608;       // 8,388,608
    float* xpj  = ws + 16777216;      // 8,388,608
    float* off  = ws + 25165824;      // 9,437,184 (NPIX*288)
    float* msk  = ws + 34603008;      // 4,718,592 (NPIX*144)
    float* y    = inp;                // reuse (inp dead after in_proj gemm)
    float* z    = x1;                 // reuse (x1 dead after off/msk gemms)
    float* attn = xpj;                // reuse (xproj dead after dcn)
    float* out  = (float*)d_out;

    // 1. conv0 5x5 dw: x NCHW -> inp NHWC (tiled LDS version)
    conv0_kernel<<<dim3(16, 16, BB), 256, 0, stream>>>(x, conv0w, conv0b, inp);
    // 2. dw3x3 + LN + GELU -> x1
    dwln_kernel<<<NPIX, 256, 0, stream>>>(inp, dww, dwb, lng, lnb, x1);
    // 3. xproj = inp @ in_w + in_b
    gemm_kernel<0><<<dim3(4, NPIX/64), 256, 0, stream>>>(inp, inw, inb, xpj, NPIX, 256, 256);
    // 4. offset = x1 @ off_w + off_b
    gemm_kernel<0><<<dim3(5, NPIX/64), 256, 0, stream>>>(x1, offw, offb, off, NPIX, 288, 256);
    // 5. mask logits = x1 @ msk_w + msk_b
    gemm_kernel<0><<<dim3(3, NPIX/64), 256, 0, stream>>>(x1, mskw, mskb, msk, NPIX, 144, 256);
    // 6. softmax over P per (pix, g)
    softmax_kernel<<<(NPIX*GG)/256, 256, 0, stream>>>(msk);
    // 7. DCN core -> y
    dcn_kernel<<<NPIX, 256, 0, stream>>>(xpj, off, msk, y);
    // 8. z = y @ outp_w + outp_b
    gemm_kernel<0><<<dim3(4, NPIX/64), 256, 0, stream>>>(y, outpw, outpb, z, NPIX, 256, 256);
    // 9. attn = z @ pw_w^T + pw_b
    gemm_kernel<1><<<dim3(4, NPIX/64), 256, 0, stream>>>(z, pww, pwb, attn, NPIX, 256, 256);
    // 10. out = x * attn (NCHW)
    finmul_kernel<<<dim3(NPIX/16, 16), 256, 0, stream>>>(x, attn, out);
}

// Round 3
// 403.945 us; speedup vs baseline: 5.0495x; 2.3094x over previous
//
#include <hip/hip_runtime.h>
#include <hip/hip_bf16.h>
#include <math.h>

// Problem constants
#define BB 8
#define CC 256
#define HH 64
#define WW 64
#define GG 16
#define GCH 16
#define PP 9
#define NPIX (BB*HH*WW)   // 32768

typedef __attribute__((ext_vector_type(4))) float f32x4;
typedef __bf16 bf16x8 __attribute__((ext_vector_type(8)));

#define GLOAD_LDS16(g, l) __builtin_amdgcn_global_load_lds( \
    (const __attribute__((address_space(1))) unsigned int*)(g), \
    (__attribute__((address_space(3))) unsigned int*)(l), 16, 0, 0)

// ---------------------------------------------------------------------------
// K1: 5x5 depthwise conv, pad 2. x: NCHW fp32 -> out NHWC fp32 + bf16 copy
#define C0PLANE 421
__global__ void conv0_kernel(const float* __restrict__ x, const float* __restrict__ w,
                             const float* __restrict__ b, float* __restrict__ out,
                             __hip_bfloat16* __restrict__ out_bf) {
    __shared__ float sx[16 * C0PLANE];
    int t  = threadIdx.x;
    int tx = blockIdx.x & 3;
    int ty = blockIdx.x >> 2;
    int cg = blockIdx.y;
    int n  = blockIdx.z;
    int h0 = ty * 16, w0 = tx * 16;
    int c0 = cg * 16;
    {
        int pair = t;
        #pragma unroll
        for (int pass = 0; pass < 2; ++pass) {
            if (pair < 320) {
                int c   = pair / 20;
                int row = pair - c * 20;
                int gy  = h0 - 2 + row;
                const float* src = x + (((size_t)(n * CC + c0 + c)) * HH + gy) * WW;
                float* dst = &sx[c * C0PLANE + row * 21];
                bool yok = (gy >= 0) & (gy < HH);
                #pragma unroll
                for (int j = 0; j < 20; ++j) {
                    int gx = w0 - 2 + j;
                    dst[j] = (yok && gx >= 0 && gx < WW) ? src[gx] : 0.0f;
                }
            }
            pair = 256 + t;
        }
    }
    __syncthreads();
    int c = t & 15;
    float wreg[25];
    const float* wp = w + (c0 + c) * 25;
    #pragma unroll
    for (int i = 0; i < 25; ++i) wreg[i] = wp[i];
    float bias = b[c0 + c];
    const float* cp = &sx[c * C0PLANE];
    #pragma unroll
    for (int it = 0; it < 16; ++it) {
        int q  = (t >> 4) + it * 16;
        int ph = q >> 4, pw = q & 15;
        float acc = bias;
        #pragma unroll
        for (int dy = 0; dy < 5; ++dy)
            #pragma unroll
            for (int dx = 0; dx < 5; ++dx)
                acc += cp[(ph + dy) * 21 + (pw + dx)] * wreg[dy * 5 + dx];
        size_t pix = (size_t)n * 4096 + (h0 + ph) * 64 + (w0 + pw);
        out[(pix << 8) + c0 + c] = acc;
        out_bf[(pix << 8) + c0 + c] = __float2bfloat16(acc);
    }
}

// ---------------------------------------------------------------------------
// K2: 3x3 depthwise conv NHWC + LayerNorm(C) + exact GELU -> x1 (bf16)
__global__ void dwln_kernel(const float* __restrict__ inp, const float* __restrict__ dww,
                            const float* __restrict__ dwb, const float* __restrict__ lng,
                            const float* __restrict__ lnb, __hip_bfloat16* __restrict__ x1) {
    int pix = blockIdx.x;
    int c = threadIdx.x;
    int wo = pix & 63;
    int ho = (pix >> 6) & 63;
    int n  = pix >> 12;
    float acc = dwb[c];
    #pragma unroll
    for (int dy = 0; dy < 3; ++dy) {
        int yy = ho + dy - 1;
        if (yy < 0 || yy >= HH) continue;
        #pragma unroll
        for (int dx = 0; dx < 3; ++dx) {
            int xx = wo + dx - 1;
            if (xx < 0 || xx >= WW) continue;
            acc += inp[(((size_t)(n*HH + yy))*WW + xx)*CC + c] * dww[c*9 + dy*3 + dx];
        }
    }
    __shared__ float ls[8];
    float s1 = acc, s2 = acc*acc;
    #pragma unroll
    for (int o = 1; o < 64; o <<= 1) {
        s1 += __shfl_xor(s1, o);
        s2 += __shfl_xor(s2, o);
    }
    int wid = threadIdx.x >> 6, lane = threadIdx.x & 63;
    if (lane == 0) { ls[wid] = s1; ls[4 + wid] = s2; }
    __syncthreads();
    float t1 = ls[0] + ls[1] + ls[2] + ls[3];
    float t2 = ls[4] + ls[5] + ls[6] + ls[7];
    float mu  = t1 * (1.0f/256.0f);
    float var = t2 * (1.0f/256.0f) - mu*mu;
    float r = rsqrtf(var + 1e-5f);
    float v = (acc - mu) * r * lng[c] + lnb[c];
    float g = 0.5f * v * (1.0f + erff(v * 0.70710678118654752440f));
    x1[(size_t)pix*CC + c] = __float2bfloat16(g);
}

// ---------------------------------------------------------------------------
// Weight conversion: W[K=256][N] fp32 -> Bt[n][k] bf16, rows >= N zero-filled
__global__ void wcvt_t_kernel(const float* __restrict__ W, __hip_bfloat16* __restrict__ Bt, int N) {
    int idx = blockIdx.x * 256 + threadIdx.x;
    int n = idx >> 8, k = idx & 255;
    float v = (n < N) ? W[k * N + n] : 0.0f;
    Bt[idx] = __float2bfloat16(v);
}
// pw_w is already [d][c] = [N][K]: straight convert
__global__ void wcvt_n_kernel(const float* __restrict__ W, __hip_bfloat16* __restrict__ Bt) {
    int idx = blockIdx.x * 256 + threadIdx.x;
    Bt[idx] = __float2bfloat16(W[idx]);
}

// ---------------------------------------------------------------------------
// K3: bf16 MFMA GEMM. A[M,256] bf16, Bt[Npad,256] bf16 (pre-transposed),
// C[M,N] (fp32 or bf16) with row stride ldc. Tile 128x64, 4 waves, BK=64, dbuf.
__device__ __forceinline__ void stage_tile(const __hip_bfloat16* __restrict__ A,
                                           const __hip_bfloat16* __restrict__ Bt,
                                           __bf16* As, __bf16* Bs,
                                           int bm, int bn, int k0, int w, int l) {
    #pragma unroll
    for (int i = 0; i < 4; ++i) {
        int q = w*256 + i*64 + l;
        int row = q >> 3, sk = q & 7;
        const __hip_bfloat16* g = A + (((size_t)(bm + row)) << 8) + k0 + sk*8;
        GLOAD_LDS16(g, As + (w*256 + i*64)*8);
    }
    #pragma unroll
    for (int i = 0; i < 2; ++i) {
        int q = w*128 + i*64 + l;
        int row = q >> 3, sk = q & 7;
        const __hip_bfloat16* g = Bt + (((size_t)(bn + row)) << 8) + k0 + sk*8;
        GLOAD_LDS16(g, Bs + (w*128 + i*64)*8);
    }
}

template <int OUT_BF16, int NBOUND>
__global__ void mgemm_kernel(const __hip_bfloat16* __restrict__ A,
                             const __hip_bfloat16* __restrict__ Bt,
                             const float* __restrict__ bias,
                             void* __restrict__ Cout, int N, int ldc) {
    __shared__ __bf16 smem[24576];    // 2 x (A 8192 + B 4096)
    int tid = threadIdx.x;
    int w = tid >> 6, l = tid & 63;
    int bn = blockIdx.x * 64;
    int bm = blockIdx.y * 128;
    __bf16* Asb[2] = { smem,        smem + 12288 };
    __bf16* Bsb[2] = { smem + 8192, smem + 20480 };
    f32x4 acc[2][4];
    #pragma unroll
    for (int m = 0; m < 2; ++m)
        #pragma unroll
        for (int n = 0; n < 4; ++n)
            acc[m][n] = (f32x4){0.f, 0.f, 0.f, 0.f};

    stage_tile(A, Bt, Asb[0], Bsb[0], bm, bn, 0, w, l);
    __syncthreads();
    int lr = l & 15, kg = l >> 4;
    #pragma unroll
    for (int t = 0; t < 4; ++t) {
        int cur = t & 1;
        if (t < 3) stage_tile(A, Bt, Asb[cur^1], Bsb[cur^1], bm, bn, (t+1)*64, w, l);
        const __bf16* Ab = Asb[cur];
        const __bf16* Bb = Bsb[cur];
        bf16x8 af[2][2], bfr[4][2];
        #pragma unroll
        for (int m = 0; m < 2; ++m)
            #pragma unroll
            for (int u = 0; u < 2; ++u)
                af[m][u] = *(const bf16x8*)&Ab[(w*32 + m*16 + lr)*64 + u*32 + kg*8];
        #pragma unroll
        for (int n = 0; n < 4; ++n)
            #pragma unroll
            for (int u = 0; u < 2; ++u)
                bfr[n][u] = *(const bf16x8*)&Bb[(n*16 + lr)*64 + u*32 + kg*8];
        #pragma unroll
        for (int u = 0; u < 2; ++u)
            #pragma unroll
            for (int m = 0; m < 2; ++m)
                #pragma unroll
                for (int n = 0; n < 4; ++n)
                    acc[m][n] = __builtin_amdgcn_mfma_f32_16x16x32_bf16(af[m][u], bfr[n][u], acc[m][n], 0, 0, 0);
        __syncthreads();
    }
    int orow = bm + w*32 + kg*4;
    #pragma unroll
    for (int n = 0; n < 4; ++n) {
        int ccol = bn + n*16 + lr;
        if (NBOUND && ccol >= N) continue;
        float bv = bias[ccol];
        #pragma unroll
        for (int m = 0; m < 2; ++m) {
            #pragma unroll
            for (int j = 0; j < 4; ++j) {
                size_t o = (size_t)(orow + m*16 + j) * ldc + ccol;
                float v = acc[m][n][j] + bv;
                if (OUT_BF16) ((__hip_bfloat16*)Cout)[o] = __float2bfloat16(v);
                else          ((float*)Cout)[o] = v;
            }
        }
    }
}

// ---------------------------------------------------------------------------
// K4: in-place softmax over P=9 per (pixel, group)
__global__ void softmax_kernel(float* __restrict__ m) {
    int idx = blockIdx.x * blockDim.x + threadIdx.x;
    float* p = m + (size_t)idx * 9;
    float v[9];
    float mx = -1e30f;
    #pragma unroll
    for (int i = 0; i < 9; ++i) { v[i] = p[i]; mx = fmaxf(mx, v[i]); }
    float s = 0.0f;
    #pragma unroll
    for (int i = 0; i < 9; ++i) { v[i] = expf(v[i] - mx); s += v[i]; }
    float r = 1.0f / s;
    #pragma unroll
    for (int i = 0; i < 9; ++i) p[i] = v[i] * r;
}

// ---------------------------------------------------------------------------
// K5: DCNv3 core. xproj NHWC fp32 -> y bf16
__global__ void dcn_kernel(const float* __restrict__ xproj, const float* __restrict__ off,
                           const float* __restrict__ msk, __hip_bfloat16* __restrict__ y) {
    int pix = blockIdx.x;
    int c = threadIdx.x;
    int g = c >> 4;
    int wo = pix & 63;
    int ho = (pix >> 6) & 63;
    int n  = pix >> 12;
    const float* ob = off + (size_t)pix*288 + g*18;
    const float* mb = msk + (size_t)pix*144 + g*9;
    const float* xb = xproj + (size_t)n*HH*WW*CC + c;
    float acc = 0.0f;
    #pragma unroll
    for (int p = 0; p < 9; ++p) {
        float offx = ob[p*2 + 0];
        float offy = ob[p*2 + 1];
        float mval = mb[p];
        int dx = (p / 3) - 1;
        int dy = (p % 3) - 1;
        float fx = (float)(wo + dx) + offx;
        float fy = (float)(ho + dy) + offy;
        float x0f = floorf(fx), y0f = floorf(fy);
        int x0 = (int)x0f, y0 = (int)y0f;
        float wx1 = fx - x0f, wx0 = 1.0f - wx1;
        float wy1 = fy - y0f, wy0 = 1.0f - wy1;
        int x1i = x0 + 1, y1i = y0 + 1;
        float v00 = (y0  >= 0 && y0  < HH && x0  >= 0 && x0  < WW) ? xb[((size_t)y0 *WW + x0 )*CC] : 0.0f;
        float v01 = (y0  >= 0 && y0  < HH && x1i >= 0 && x1i < WW) ? xb[((size_t)y0 *WW + x1i)*CC] : 0.0f;
        float v10 = (y1i >= 0 && y1i < HH && x0  >= 0 && x0  < WW) ? xb[((size_t)y1i*WW + x0 )*CC] : 0.0f;
        float v11 = (y1i >= 0 && y1i < HH && x1i >= 0 && x1i < WW) ? xb[((size_t)y1i*WW + x1i)*CC] : 0.0f;
        acc += mval * (wy0*(wx0*v00 + wx1*v01) + wy1*(wx0*v10 + wx1*v11));
    }
    y[(size_t)pix*CC + c] = __float2bfloat16(acc);
}

// ---------------------------------------------------------------------------
// K6: out[n,d,h,w] = x[n,d,h,w] * attn[pix, d]
__global__ void finmul_kernel(const float* __restrict__ x, const float* __restrict__ attn,
                              float* __restrict__ out) {
    __shared__ float t[16][17];
    int pix0 = blockIdx.x * 16;
    int d0   = blockIdx.y * 16;
    int li = threadIdx.x & 15;
    int lj = threadIdx.x >> 4;
    t[lj][li] = attn[(size_t)(pix0 + lj)*CC + d0 + li];
    __syncthreads();
    int pix = pix0 + li;
    int wo = pix & 63;
    int ho = (pix >> 6) & 63;
    int n  = pix >> 12;
    int d = d0 + lj;
    size_t oidx = (((size_t)n*CC + d)*HH + ho)*WW + wo;
    out[oidx] = x[oidx] * t[li][lj];
}

// ---------------------------------------------------------------------------
extern "C" void kernel_launch(void* const* d_in, const int* in_sizes, int n_in,
                              void* d_out, int out_size, void* d_ws, size_t ws_size,
                              hipStream_t stream) {
    const float* x      = (const float*)d_in[0];
    const float* conv0w = (const float*)d_in[1];
    const float* conv0b = (const float*)d_in[2];
    const float* dww    = (const float*)d_in[3];
    const float* dwb    = (const float*)d_in[4];
    const float* lng    = (const float*)d_in[5];
    const float* lnb    = (const float*)d_in[6];
    const float* offw   = (const float*)d_in[7];
    const float* offb   = (const float*)d_in[8];
    const float* mskw   = (const float*)d_in[9];
    const float* mskb   = (const float*)d_in[10];
    const float* inw    = (const float*)d_in[11];
    const float* inb    = (const float*)d_in[12];
    const float* outpw  = (const float*)d_in[13];
    const float* outpb  = (const float*)d_in[14];
    const float* pww    = (const float*)d_in[15];
    const float* pwb    = (const float*)d_in[16];

    float* ws   = (float*)d_ws;
    float* off  = ws;                                 // 9,437,184 floats
    float* inpf = ws + 9437184;                       // 8,388,608 (msk aliases)
    float* msk  = inpf;                               // 4,718,592 (written after dwln)
    float* xpj  = ws + 17825792;                      // 8,388,608 (attn aliases)
    float* attn = xpj;
    __hip_bfloat16* bfb    = (__hip_bfloat16*)(ws + 26214400);
    __hip_bfloat16* inp_bf = bfb;                     // 8,388,608 elems (y_bf aliases)
    __hip_bfloat16* y_bf   = inp_bf;
    __hip_bfloat16* x1_bf  = bfb + 8388608;           // (z_bf aliases)
    __hip_bfloat16* z_bf   = x1_bf;
    __hip_bfloat16* bt_in   = bfb + 16777216;         // 256*256
    __hip_bfloat16* bt_off  = bt_in  + 65536;         // 320*256
    __hip_bfloat16* bt_msk  = bt_off + 81920;         // 192*256
    __hip_bfloat16* bt_outp = bt_msk + 49152;         // 256*256
    __hip_bfloat16* bt_pw   = bt_outp + 65536;        // 256*256
    float* out = (float*)d_out;

    // weight conversion (bf16, transposed [N][K], zero-padded rows)
    wcvt_t_kernel<<<256, 256, 0, stream>>>(inw,   bt_in,   256);
    wcvt_t_kernel<<<320, 256, 0, stream>>>(offw,  bt_off,  288);
    wcvt_t_kernel<<<192, 256, 0, stream>>>(mskw,  bt_msk,  144);
    wcvt_t_kernel<<<256, 256, 0, stream>>>(outpw, bt_outp, 256);
    wcvt_n_kernel<<<256, 256, 0, stream>>>(pww,   bt_pw);

    // 1. conv0 5x5 dw -> inpf (fp32) + inp_bf
    conv0_kernel<<<dim3(16, 16, BB), 256, 0, stream>>>(x, conv0w, conv0b, inpf, inp_bf);
    // 2. dw3x3 + LN + GELU -> x1_bf
    dwln_kernel<<<NPIX, 256, 0, stream>>>(inpf, dww, dwb, lng, lnb, x1_bf);
    // 3. xproj = inp @ in_w + in_b  (fp32 out)
    mgemm_kernel<0,0><<<dim3(4, 256), 256, 0, stream>>>(inp_bf, bt_in, inb, xpj, 256, 256);
    // 4. offset = x1 @ off_w + off_b
    mgemm_kernel<0,1><<<dim3(5, 256), 256, 0, stream>>>(x1_bf, bt_off, offb, off, 288, 288);
    // 5. mask logits = x1 @ msk_w + msk_b
    mgemm_kernel<0,1><<<dim3(3, 256), 256, 0, stream>>>(x1_bf, bt_msk, mskb, msk, 144, 144);
    // 6. softmax over P per (pix, g)
    softmax_kernel<<<(NPIX*GG)/256, 256, 0, stream>>>(msk);
    // 7. DCN core -> y_bf
    dcn_kernel<<<NPIX, 256, 0, stream>>>(xpj, off, msk, y_bf);
    // 8. z = y @ outp_w + outp_b (bf16 out)
    mgemm_kernel<1,0><<<dim3(4, 256), 256, 0, stream>>>(y_bf, bt_outp, outpb, z_bf, 256, 256);
    // 9. attn = z @ pw_w^T + pw_b (fp32 out)
    mgemm_kernel<0,0><<<dim3(4, 256), 256, 0, stream>>>(z_bf, bt_pw, pwb, attn, 256, 256);
    // 10. out = x * attn (NCHW)
    finmul_kernel<<<dim3(NPIX/16, 16), 256, 0, stream>>>(x, attn, out);
}

// Round 4
// 324.731 us; speedup vs baseline: 6.2813x; 1.2439x over previous
//
#include <hip/hip_runtime.h>
#include <hip/hip_bf16.h>
#include <math.h>

// Problem constants
#define BB 8
#define CC 256
#define HH 64
#define WW 64
#define GG 16
#define GCH 16
#define PP 9
#define NPIX (BB*HH*WW)   // 32768

typedef __attribute__((ext_vector_type(4))) float f32x4;
typedef __bf16 bf16x8 __attribute__((ext_vector_type(8)));

#define GLOAD_LDS16(g, l) __builtin_amdgcn_global_load_lds( \
    (const __attribute__((address_space(1))) unsigned int*)(g), \
    (__attribute__((address_space(3))) unsigned int*)(l), 16, 0, 0)

// ---------------------------------------------------------------------------
// K1: 5x5 depthwise conv, pad 2. x: NCHW fp32 -> out NHWC fp32 + bf16 copy
#define C0PLANE 421
__global__ void conv0_kernel(const float* __restrict__ x, const float* __restrict__ w,
                             const float* __restrict__ b, float* __restrict__ out,
                             __hip_bfloat16* __restrict__ out_bf) {
    __shared__ float sx[16 * C0PLANE];
    int t  = threadIdx.x;
    int tx = blockIdx.x & 3;
    int ty = blockIdx.x >> 2;
    int cg = blockIdx.y;
    int n  = blockIdx.z;
    int h0 = ty * 16, w0 = tx * 16;
    int c0 = cg * 16;
    {
        int pair = t;
        #pragma unroll
        for (int pass = 0; pass < 2; ++pass) {
            if (pair < 320) {
                int c   = pair / 20;
                int row = pair - c * 20;
                int gy  = h0 - 2 + row;
                const float* src = x + (((size_t)(n * CC + c0 + c)) * HH + gy) * WW;
                float* dst = &sx[c * C0PLANE + row * 21];
                bool yok = (gy >= 0) & (gy < HH);
                #pragma unroll
                for (int j = 0; j < 20; ++j) {
                    int gx = w0 - 2 + j;
                    dst[j] = (yok && gx >= 0 && gx < WW) ? src[gx] : 0.0f;
                }
            }
            pair = 256 + t;
        }
    }
    __syncthreads();
    int c = t & 15;
    float wreg[25];
    const float* wp = w + (c0 + c) * 25;
    #pragma unroll
    for (int i = 0; i < 25; ++i) wreg[i] = wp[i];
    float bias = b[c0 + c];
    const float* cp = &sx[c * C0PLANE];
    #pragma unroll
    for (int it = 0; it < 16; ++it) {
        int q  = (t >> 4) + it * 16;
        int ph = q >> 4, pw = q & 15;
        float acc = bias;
        #pragma unroll
        for (int dy = 0; dy < 5; ++dy)
            #pragma unroll
            for (int dx = 0; dx < 5; ++dx)
                acc += cp[(ph + dy) * 21 + (pw + dx)] * wreg[dy * 5 + dx];
        size_t pix = (size_t)n * 4096 + (h0 + ph) * 64 + (w0 + pw);
        out[(pix << 8) + c0 + c] = acc;
        out_bf[(pix << 8) + c0 + c] = __float2bfloat16(acc);
    }
}

// ---------------------------------------------------------------------------
// K2: 3x3 depthwise conv NHWC + LayerNorm(C) + exact GELU -> x1 (bf16)
__global__ void dwln_kernel(const float* __restrict__ inp, const float* __restrict__ dww,
                            const float* __restrict__ dwb, const float* __restrict__ lng,
                            const float* __restrict__ lnb, __hip_bfloat16* __restrict__ x1) {
    int pix = blockIdx.x;
    int c = threadIdx.x;
    int wo = pix & 63;
    int ho = (pix >> 6) & 63;
    int n  = pix >> 12;
    float acc = dwb[c];
    #pragma unroll
    for (int dy = 0; dy < 3; ++dy) {
        int yy = ho + dy - 1;
        if (yy < 0 || yy >= HH) continue;
        #pragma unroll
        for (int dx = 0; dx < 3; ++dx) {
            int xx = wo + dx - 1;
            if (xx < 0 || xx >= WW) continue;
            acc += inp[(((size_t)(n*HH + yy))*WW + xx)*CC + c] * dww[c*9 + dy*3 + dx];
        }
    }
    __shared__ float ls[8];
    float s1 = acc, s2 = acc*acc;
    #pragma unroll
    for (int o = 1; o < 64; o <<= 1) {
        s1 += __shfl_xor(s1, o);
        s2 += __shfl_xor(s2, o);
    }
    int wid = threadIdx.x >> 6, lane = threadIdx.x & 63;
    if (lane == 0) { ls[wid] = s1; ls[4 + wid] = s2; }
    __syncthreads();
    float t1 = ls[0] + ls[1] + ls[2] + ls[3];
    float t2 = ls[4] + ls[5] + ls[6] + ls[7];
    float mu  = t1 * (1.0f/256.0f);
    float var = t2 * (1.0f/256.0f) - mu*mu;
    float r = rsqrtf(var + 1e-5f);
    float v = (acc - mu) * r * lng[c] + lnb[c];
    float g = 0.5f * v * (1.0f + erff(v * 0.70710678118654752440f));
    x1[(size_t)pix*CC + c] = __float2bfloat16(g);
}

// ---------------------------------------------------------------------------
// Weight conversion: W[K=256][N] fp32 -> Bt[n][k] bf16, rows >= N zero-filled
__global__ void wcvt_t_kernel(const float* __restrict__ W, __hip_bfloat16* __restrict__ Bt, int N) {
    int idx = blockIdx.x * 256 + threadIdx.x;
    int n = idx >> 8, k = idx & 255;
    float v = (n < N) ? W[k * N + n] : 0.0f;
    Bt[idx] = __float2bfloat16(v);
}
__global__ void wcvt_n_kernel(const float* __restrict__ W, __hip_bfloat16* __restrict__ Bt) {
    int idx = blockIdx.x * 256 + threadIdx.x;
    Bt[idx] = __float2bfloat16(W[idx]);
}

// ---------------------------------------------------------------------------
// K3: bf16 MFMA GEMM. A[M,256] bf16, Bt[Npad,256] bf16 (pre-transposed),
// C[M,N] (fp32 or bf16) row stride ldc. Tile 128x64, 4 waves, BK=64, dbuf.
__device__ __forceinline__ void stage_tile(const __hip_bfloat16* __restrict__ A,
                                           const __hip_bfloat16* __restrict__ Bt,
                                           __bf16* As, __bf16* Bs,
                                           int bm, int bn, int k0, int w, int l) {
    #pragma unroll
    for (int i = 0; i < 4; ++i) {
        int q = w*256 + i*64 + l;
        int row = q >> 3, sk = q & 7;
        const __hip_bfloat16* g = A + (((size_t)(bm + row)) << 8) + k0 + sk*8;
        GLOAD_LDS16(g, As + (w*256 + i*64)*8);
    }
    #pragma unroll
    for (int i = 0; i < 2; ++i) {
        int q = w*128 + i*64 + l;
        int row = q >> 3, sk = q & 7;
        const __hip_bfloat16* g = Bt + (((size_t)(bn + row)) << 8) + k0 + sk*8;
        GLOAD_LDS16(g, Bs + (w*128 + i*64)*8);
    }
}

template <int OUT_BF16, int NBOUND>
__global__ void mgemm_kernel(const __hip_bfloat16* __restrict__ A,
                             const __hip_bfloat16* __restrict__ Bt,
                             const float* __restrict__ bias,
                             void* __restrict__ Cout, int N, int ldc) {
    __shared__ __bf16 smem[24576];
    int tid = threadIdx.x;
    int w = tid >> 6, l = tid & 63;
    int bn = blockIdx.x * 64;
    int bm = blockIdx.y * 128;
    __bf16* Asb[2] = { smem,        smem + 12288 };
    __bf16* Bsb[2] = { smem + 8192, smem + 20480 };
    f32x4 acc[2][4];
    #pragma unroll
    for (int m = 0; m < 2; ++m)
        #pragma unroll
        for (int n = 0; n < 4; ++n)
            acc[m][n] = (f32x4){0.f, 0.f, 0.f, 0.f};

    stage_tile(A, Bt, Asb[0], Bsb[0], bm, bn, 0, w, l);
    __syncthreads();
    int lr = l & 15, kg = l >> 4;
    #pragma unroll
    for (int t = 0; t < 4; ++t) {
        int cur = t & 1;
        if (t < 3) stage_tile(A, Bt, Asb[cur^1], Bsb[cur^1], bm, bn, (t+1)*64, w, l);
        const __bf16* Ab = Asb[cur];
        const __bf16* Bb = Bsb[cur];
        bf16x8 af[2][2], bfr[4][2];
        #pragma unroll
        for (int m = 0; m < 2; ++m)
            #pragma unroll
            for (int u = 0; u < 2; ++u)
                af[m][u] = *(const bf16x8*)&Ab[(w*32 + m*16 + lr)*64 + u*32 + kg*8];
        #pragma unroll
        for (int n = 0; n < 4; ++n)
            #pragma unroll
            for (int u = 0; u < 2; ++u)
                bfr[n][u] = *(const bf16x8*)&Bb[(n*16 + lr)*64 + u*32 + kg*8];
        #pragma unroll
        for (int u = 0; u < 2; ++u)
            #pragma unroll
            for (int m = 0; m < 2; ++m)
                #pragma unroll
                for (int n = 0; n < 4; ++n)
                    acc[m][n] = __builtin_amdgcn_mfma_f32_16x16x32_bf16(af[m][u], bfr[n][u], acc[m][n], 0, 0, 0);
        __syncthreads();
    }
    int orow = bm + w*32 + kg*4;
    #pragma unroll
    for (int n = 0; n < 4; ++n) {
        int ccol = bn + n*16 + lr;
        if (NBOUND && ccol >= N) continue;
        float bv = bias[ccol];
        #pragma unroll
        for (int m = 0; m < 2; ++m) {
            #pragma unroll
            for (int j = 0; j < 4; ++j) {
                size_t o = (size_t)(orow + m*16 + j) * ldc + ccol;
                float v = acc[m][n][j] + bv;
                if (OUT_BF16) ((__hip_bfloat16*)Cout)[o] = __float2bfloat16(v);
                else          ((float*)Cout)[o] = v;
            }
        }
    }
}

// ---------------------------------------------------------------------------
// K4: in-place softmax over P=9 per (pixel, group)
__global__ void softmax_kernel(float* __restrict__ m) {
    int idx = blockIdx.x * blockDim.x + threadIdx.x;
    float* p = m + (size_t)idx * 9;
    float v[9];
    float mx = -1e30f;
    #pragma unroll
    for (int i = 0; i < 9; ++i) { v[i] = p[i]; mx = fmaxf(mx, v[i]); }
    float s = 0.0f;
    #pragma unroll
    for (int i = 0; i < 9; ++i) { v[i] = expf(v[i] - mx); s += v[i]; }
    float r = 1.0f / s;
    #pragma unroll
    for (int i = 0; i < 9; ++i) p[i] = v[i] * r;
}

// ---------------------------------------------------------------------------
// K5 v2: DCNv3 core. xproj bf16 NHWC, off/msk fp32 -> y bf16.
// Block = 256 threads = 8 pixels x 32 lanes (16 groups x 2 channel-halves).
// Phase 1: one thread per (px,g,p) computes 4 folded weights + 4 clamped
//          corner offsets into LDS. Phase 2: 8-channel gather threads.
__device__ __forceinline__ void bfu2(unsigned a, float& lo, float& hi) {
    union { unsigned u; float f; } t0, t1;
    t0.u = a << 16; t1.u = a & 0xffff0000u;
    lo = t0.f; hi = t1.f;
}

__global__ void dcn_kernel(const __hip_bfloat16* __restrict__ xproj,
                           const float* __restrict__ off,
                           const float* __restrict__ msk,
                           __hip_bfloat16* __restrict__ y) {
    __shared__ float4 wLds[1152];   // 8 px * 144 (g*9+p)
    __shared__ int4   oLds[1152];
    int pix0 = blockIdx.x * 8;
    // ---- phase 1: weights + corner offsets ----
    for (int tau = threadIdx.x; tau < 1152; tau += 256) {
        int px = tau / 144;
        int gp = tau - px * 144;
        int g  = gp / 9, p = gp - g * 9;
        int pix = pix0 + px;
        int wo = pix & 63, ho = (pix >> 6) & 63;
        const float* ob = off + (size_t)pix * 288 + g * 18 + p * 2;
        float offx = ob[0];
        float offy = ob[1];
        float m = msk[(size_t)pix * 144 + gp];
        int dx = p / 3 - 1;       // kw-major
        int dy = p - (p / 3) * 3 - 1;
        float fx = (float)(wo + dx) + offx;
        float fy = (float)(ho + dy) + offy;
        float x0f = floorf(fx), y0f = floorf(fy);
        int x0 = (int)x0f, y0 = (int)y0f;
        int x1 = x0 + 1, y1 = y0 + 1;
        float wx1 = fx - x0f, wx0 = 1.0f - wx1;
        float wy1 = fy - y0f, wy0 = 1.0f - wy1;
        float vx0 = (x0 >= 0 && x0 < WW) ? 1.0f : 0.0f;
        float vx1 = (x1 >= 0 && x1 < WW) ? 1.0f : 0.0f;
        float vy0 = (y0 >= 0 && y0 < HH) ? 1.0f : 0.0f;
        float vy1 = (y1 >= 0 && y1 < HH) ? 1.0f : 0.0f;
        int x0c = min(max(x0, 0), WW - 1), x1c = min(max(x1, 0), WW - 1);
        int y0c = min(max(y0, 0), HH - 1), y1c = min(max(y1, 0), HH - 1);
        wLds[tau] = make_float4(m * wy0 * wx0 * vy0 * vx0,
                                m * wy0 * wx1 * vy0 * vx1,
                                m * wy1 * wx0 * vy1 * vx0,
                                m * wy1 * wx1 * vy1 * vx1);
        oLds[tau] = make_int4((y0c * WW + x0c) << 8, (y0c * WW + x1c) << 8,
                              (y1c * WW + x0c) << 8, (y1c * WW + x1c) << 8);
    }
    __syncthreads();
    // ---- phase 2: gather 8 channels per thread ----
    int t  = threadIdx.x;
    int px = t >> 5;
    int l  = t & 31;
    int g  = l >> 1;
    int ch = g * 16 + (l & 1) * 8;
    int pix = pix0 + px;
    int n = pix >> 12;
    const __hip_bfloat16* xb = xproj + ((size_t)n << 20) + ch;
    float a0=0,a1=0,a2=0,a3=0,a4=0,a5=0,a6=0,a7=0;
    const float4* wp = &wLds[px * 144 + g * 9];
    const int4*  op = &oLds[px * 144 + g * 9];
    #pragma unroll
    for (int p = 0; p < 9; ++p) {
        float4 w = wp[p];
        int4  o = op[p];
        {
            uint4 u = *(const uint4*)(xb + o.x);
            float b0,b1,b2,b3,b4,b5,b6,b7;
            bfu2(u.x,b0,b1); bfu2(u.y,b2,b3); bfu2(u.z,b4,b5); bfu2(u.w,b6,b7);
            a0 += w.x*b0; a1 += w.x*b1; a2 += w.x*b2; a3 += w.x*b3;
            a4 += w.x*b4; a5 += w.x*b5; a6 += w.x*b6; a7 += w.x*b7;
        }
        {
            uint4 u = *(const uint4*)(xb + o.y);
            float b0,b1,b2,b3,b4,b5,b6,b7;
            bfu2(u.x,b0,b1); bfu2(u.y,b2,b3); bfu2(u.z,b4,b5); bfu2(u.w,b6,b7);
            a0 += w.y*b0; a1 += w.y*b1; a2 += w.y*b2; a3 += w.y*b3;
            a4 += w.y*b4; a5 += w.y*b5; a6 += w.y*b6; a7 += w.y*b7;
        }
        {
            uint4 u = *(const uint4*)(xb + o.z);
            float b0,b1,b2,b3,b4,b5,b6,b7;
            bfu2(u.x,b0,b1); bfu2(u.y,b2,b3); bfu2(u.z,b4,b5); bfu2(u.w,b6,b7);
            a0 += w.z*b0; a1 += w.z*b1; a2 += w.z*b2; a3 += w.z*b3;
            a4 += w.z*b4; a5 += w.z*b5; a6 += w.z*b6; a7 += w.z*b7;
        }
        {
            uint4 u = *(const uint4*)(xb + o.w);
            float b0,b1,b2,b3,b4,b5,b6,b7;
            bfu2(u.x,b0,b1); bfu2(u.y,b2,b3); bfu2(u.z,b4,b5); bfu2(u.w,b6,b7);
            a0 += w.w*b0; a1 += w.w*b1; a2 += w.w*b2; a3 += w.w*b3;
            a4 += w.w*b4; a5 += w.w*b5; a6 += w.w*b6; a7 += w.w*b7;
        }
    }
    union { __hip_bfloat16 h[8]; uint4 u; } ov;
    ov.h[0]=__float2bfloat16(a0); ov.h[1]=__float2bfloat16(a1);
    ov.h[2]=__float2bfloat16(a2); ov.h[3]=__float2bfloat16(a3);
    ov.h[4]=__float2bfloat16(a4); ov.h[5]=__float2bfloat16(a5);
    ov.h[6]=__float2bfloat16(a6); ov.h[7]=__float2bfloat16(a7);
    *(uint4*)(y + (size_t)pix * CC + ch) = ov.u;
}

// ---------------------------------------------------------------------------
// K6: out[n,d,h,w] = x[n,d,h,w] * attn[pix, d]
__global__ void finmul_kernel(const float* __restrict__ x, const float* __restrict__ attn,
                              float* __restrict__ out) {
    __shared__ float t[16][17];
    int pix0 = blockIdx.x * 16;
    int d0   = blockIdx.y * 16;
    int li = threadIdx.x & 15;
    int lj = threadIdx.x >> 4;
    t[lj][li] = attn[(size_t)(pix0 + lj)*CC + d0 + li];
    __syncthreads();
    int pix = pix0 + li;
    int wo = pix & 63;
    int ho = (pix >> 6) & 63;
    int n  = pix >> 12;
    int d = d0 + lj;
    size_t oidx = (((size_t)n*CC + d)*HH + ho)*WW + wo;
    out[oidx] = x[oidx] * t[li][lj];
}

// ---------------------------------------------------------------------------
extern "C" void kernel_launch(void* const* d_in, const int* in_sizes, int n_in,
                              void* d_out, int out_size, void* d_ws, size_t ws_size,
                              hipStream_t stream) {
    const float* x      = (const float*)d_in[0];
    const float* conv0w = (const float*)d_in[1];
    const float* conv0b = (const float*)d_in[2];
    const float* dww    = (const float*)d_in[3];
    const float* dwb    = (const float*)d_in[4];
    const float* lng    = (const float*)d_in[5];
    const float* lnb    = (const float*)d_in[6];
    const float* offw   = (const float*)d_in[7];
    const float* offb   = (const float*)d_in[8];
    const float* mskw   = (const float*)d_in[9];
    const float* mskb   = (const float*)d_in[10];
    const float* inw    = (const float*)d_in[11];
    const float* inb    = (const float*)d_in[12];
    const float* outpw  = (const float*)d_in[13];
    const float* outpb  = (const float*)d_in[14];
    const float* pww    = (const float*)d_in[15];
    const float* pwb    = (const float*)d_in[16];

    float* ws   = (float*)d_ws;
    float* off  = ws;                          // 9,437,184 floats
    float* msk  = ws + 9437184;                // 4,718,592
    float* inpf = ws + 14155776;               // 8,388,608 (attn aliases)
    float* attn = inpf;
    __hip_bfloat16* bfb    = (__hip_bfloat16*)(ws + 22544384);
    __hip_bfloat16* inp_bf = bfb;              // 8,388,608 elems (y_bf aliases)
    __hip_bfloat16* y_bf   = inp_bf;
    __hip_bfloat16* x1_bf  = bfb + 8388608;    // (xpj_bf, z_bf alias)
    __hip_bfloat16* xpj_bf = x1_bf;
    __hip_bfloat16* z_bf   = x1_bf;
    __hip_bfloat16* bt_in   = bfb + 16777216;  // 256*256
    __hip_bfloat16* bt_off  = bt_in  + 65536;  // 320*256
    __hip_bfloat16* bt_msk  = bt_off + 81920;  // 192*256
    __hip_bfloat16* bt_outp = bt_msk + 49152;  // 256*256
    __hip_bfloat16* bt_pw   = bt_outp + 65536; // 256*256
    float* out = (float*)d_out;

    // weight conversion
    wcvt_t_kernel<<<256, 256, 0, stream>>>(inw,   bt_in,   256);
    wcvt_t_kernel<<<320, 256, 0, stream>>>(offw,  bt_off,  288);
    wcvt_t_kernel<<<192, 256, 0, stream>>>(mskw,  bt_msk,  144);
    wcvt_t_kernel<<<256, 256, 0, stream>>>(outpw, bt_outp, 256);
    wcvt_n_kernel<<<256, 256, 0, stream>>>(pww,   bt_pw);

    // 1. conv0 5x5 dw -> inpf (fp32) + inp_bf
    conv0_kernel<<<dim3(16, 16, BB), 256, 0, stream>>>(x, conv0w, conv0b, inpf, inp_bf);
    // 2. dw3x3 + LN + GELU -> x1_bf
    dwln_kernel<<<NPIX, 256, 0, stream>>>(inpf, dww, dwb, lng, lnb, x1_bf);
    // 3. offset = x1 @ off_w + off_b (fp32)
    mgemm_kernel<0,1><<<dim3(5, 256), 256, 0, stream>>>(x1_bf, bt_off, offb, off, 288, 288);
    // 4. mask logits = x1 @ msk_w + msk_b (fp32)
    mgemm_kernel<0,1><<<dim3(3, 256), 256, 0, stream>>>(x1_bf, bt_msk, mskb, msk, 144, 144);
    // 5. softmax
    softmax_kernel<<<(NPIX*GG)/256, 256, 0, stream>>>(msk);
    // 6. xproj = inp @ in_w + in_b -> bf16 (overwrites x1_bf region; x1 dead)
    mgemm_kernel<1,0><<<dim3(4, 256), 256, 0, stream>>>(inp_bf, bt_in, inb, xpj_bf, 256, 256);
    // 7. DCN core -> y_bf (overwrites inp_bf region; inp dead)
    dcn_kernel<<<NPIX/8, 256, 0, stream>>>(xpj_bf, off, msk, y_bf);
    // 8. z = y @ outp_w + outp_b -> bf16 (overwrites xpj region; xpj dead)
    mgemm_kernel<1,0><<<dim3(4, 256), 256, 0, stream>>>(y_bf, bt_outp, outpb, z_bf, 256, 256);
    // 9. attn = z @ pw_w^T + pw_b -> fp32 (overwrites inpf; inpf dead)
    mgemm_kernel<0,0><<<dim3(4, 256), 256, 0, stream>>>(z_bf, bt_pw, pwb, attn, 256, 256);
    // 10. out = x * attn (NCHW)
    finmul_kernel<<<dim3(NPIX/16, 16), 256, 0, stream>>>(x, attn, out);
}

// Round 5
// 263.248 us; speedup vs baseline: 7.7483x; 1.2336x over previous
//
#include <hip/hip_runtime.h>
#include <hip/hip_bf16.h>
#include <math.h>

// Problem constants
#define BB 8
#define CC 256
#define HH 64
#define WW 64
#define GG 16
#define GCH 16
#define PP 9
#define NPIX (BB*HH*WW)   // 32768

typedef __attribute__((ext_vector_type(4))) float f32x4;
typedef __bf16 bf16x8 __attribute__((ext_vector_type(8)));

#define GLOAD_LDS16(g, l) __builtin_amdgcn_global_load_lds( \
    (const __attribute__((address_space(1))) unsigned int*)(g), \
    (__attribute__((address_space(3))) unsigned int*)(l), 16, 0, 0)

// ---------------------------------------------------------------------------
// K1 v3: 5x5 depthwise conv, pad 2. x: NCHW fp32 -> out NHWC fp32 + bf16.
// Block = 256 thr = 16 channels x 16 col-strips; tile = 8 rows x 64 cols.
// Halo = 12 rows x full width, staged as coalesced float4 row loads.
// LDS plane stride 817 (817%32=17, odd) -> compute reads <=2-way banked.
#define C0PLANE 817   // 12*68 + 1
__global__ void conv0_kernel(const float* __restrict__ x, const float* __restrict__ w,
                             const float* __restrict__ b, float* __restrict__ out,
                             __hip_bfloat16* __restrict__ out_bf) {
    __shared__ float sx[16 * C0PLANE];   // 52288 B
    int t  = threadIdx.x;
    int st = blockIdx.x;                 // row strip 0..7
    int cg = blockIdx.y;                 // channel group
    int n  = blockIdx.z;
    int h0 = st * 8;
    int c0 = cg * 16;

    // ---- load halo: 16ch x 12 rows x 64 floats, float4-coalesced ----
    #pragma unroll
    for (int i = 0; i < 12; ++i) {
        int task = i * 256 + t;          // 0..3071
        int lane = task & 15;
        int pair = task >> 4;            // 0..191
        int c    = pair / 12;
        int row  = pair - c * 12;
        int gy   = h0 - 2 + row;
        float4 v = make_float4(0.f, 0.f, 0.f, 0.f);
        if (gy >= 0 && gy < HH)
            v = *(const float4*)(x + (((size_t)(n * CC + c0 + c)) * HH + gy) * WW + lane * 4);
        *(float4*)&sx[c * C0PLANE + row * 68 + 2 + lane * 4] = v;
    }
    if (t < 192) {                        // zero pad cols 0,1,66,67
        int c = t / 12, row = t - (t / 12) * 12;
        float* p = &sx[c * C0PLANE + row * 68];
        p[0] = 0.f; p[1] = 0.f; p[66] = 0.f; p[67] = 0.f;
    }
    __syncthreads();

    // ---- compute: c = t&15, col-strip s = t>>4 (4 cols), 8 rows ----
    int c = t & 15;
    int s = t >> 4;
    float wreg[25];
    const float* wp = w + (c0 + c) * 25;
    #pragma unroll
    for (int i = 0; i < 25; ++i) wreg[i] = wp[i];
    float bias = b[c0 + c];
    const float* cp = &sx[c * C0PLANE + s * 4];

    float win[5][8];
    #pragma unroll
    for (int rr = 0; rr < 4; ++rr)
        #pragma unroll
        for (int j = 0; j < 8; ++j) win[rr][j] = cp[rr * 68 + j];

    #pragma unroll
    for (int r = 0; r < 8; ++r) {
        #pragma unroll
        for (int j = 0; j < 8; ++j) win[(r + 4) % 5][j] = cp[(r + 4) * 68 + j];
        float a0 = bias, a1 = bias, a2 = bias, a3 = bias;
        #pragma unroll
        for (int dy = 0; dy < 5; ++dy) {
            const float* wr = &wreg[dy * 5];
            const float* wd = win[(r + dy) % 5];
            #pragma unroll
            for (int dx = 0; dx < 5; ++dx) {
                float wv = wr[dx];
                a0 += wd[0 + dx] * wv;
                a1 += wd[1 + dx] * wv;
                a2 += wd[2 + dx] * wv;
                a3 += wd[3 + dx] * wv;
            }
        }
        size_t pixb = ((size_t)n * 4096 + (h0 + r) * 64 + s * 4) << 8;
        out[pixb + c0 + c]         = a0;
        out[pixb + 256 + c0 + c]   = a1;
        out[pixb + 512 + c0 + c]   = a2;
        out[pixb + 768 + c0 + c]   = a3;
        out_bf[pixb + c0 + c]       = __float2bfloat16(a0);
        out_bf[pixb + 256 + c0 + c] = __float2bfloat16(a1);
        out_bf[pixb + 512 + c0 + c] = __float2bfloat16(a2);
        out_bf[pixb + 768 + c0 + c] = __float2bfloat16(a3);
    }
}

// ---------------------------------------------------------------------------
// K2: 3x3 depthwise conv NHWC + LayerNorm(C) + exact GELU -> x1 (bf16)
__global__ void dwln_kernel(const float* __restrict__ inp, const float* __restrict__ dww,
                            const float* __restrict__ dwb, const float* __restrict__ lng,
                            const float* __restrict__ lnb, __hip_bfloat16* __restrict__ x1) {
    int pix = blockIdx.x;
    int c = threadIdx.x;
    int wo = pix & 63;
    int ho = (pix >> 6) & 63;
    int n  = pix >> 12;
    float acc = dwb[c];
    #pragma unroll
    for (int dy = 0; dy < 3; ++dy) {
        int yy = ho + dy - 1;
        if (yy < 0 || yy >= HH) continue;
        #pragma unroll
        for (int dx = 0; dx < 3; ++dx) {
            int xx = wo + dx - 1;
            if (xx < 0 || xx >= WW) continue;
            acc += inp[(((size_t)(n*HH + yy))*WW + xx)*CC + c] * dww[c*9 + dy*3 + dx];
        }
    }
    __shared__ float ls[8];
    float s1 = acc, s2 = acc*acc;
    #pragma unroll
    for (int o = 1; o < 64; o <<= 1) {
        s1 += __shfl_xor(s1, o);
        s2 += __shfl_xor(s2, o);
    }
    int wid = threadIdx.x >> 6, lane = threadIdx.x & 63;
    if (lane == 0) { ls[wid] = s1; ls[4 + wid] = s2; }
    __syncthreads();
    float t1 = ls[0] + ls[1] + ls[2] + ls[3];
    float t2 = ls[4] + ls[5] + ls[6] + ls[7];
    float mu  = t1 * (1.0f/256.0f);
    float var = t2 * (1.0f/256.0f) - mu*mu;
    float r = rsqrtf(var + 1e-5f);
    float v = (acc - mu) * r * lng[c] + lnb[c];
    float g = 0.5f * v * (1.0f + erff(v * 0.70710678118654752440f));
    x1[(size_t)pix*CC + c] = __float2bfloat16(g);
}

// ---------------------------------------------------------------------------
// Weight conversion: W[K=256][N] fp32 -> Bt[n][k] bf16, rows >= N zero-filled
__global__ void wcvt_t_kernel(const float* __restrict__ W, __hip_bfloat16* __restrict__ Bt, int N) {
    int idx = blockIdx.x * 256 + threadIdx.x;
    int n = idx >> 8, k = idx & 255;
    float v = (n < N) ? W[k * N + n] : 0.0f;
    Bt[idx] = __float2bfloat16(v);
}
__global__ void wcvt_n_kernel(const float* __restrict__ W, __hip_bfloat16* __restrict__ Bt) {
    int idx = blockIdx.x * 256 + threadIdx.x;
    Bt[idx] = __float2bfloat16(W[idx]);
}

// ---------------------------------------------------------------------------
// K3: bf16 MFMA GEMM. A[M,256] bf16, Bt[Npad,256] bf16 (pre-transposed),
// C[M,N] (fp32 or bf16) row stride ldc. Tile 128x64, 4 waves, BK=64, dbuf.
__device__ __forceinline__ void stage_tile(const __hip_bfloat16* __restrict__ A,
                                           const __hip_bfloat16* __restrict__ Bt,
                                           __bf16* As, __bf16* Bs,
                                           int bm, int bn, int k0, int w, int l) {
    #pragma unroll
    for (int i = 0; i < 4; ++i) {
        int q = w*256 + i*64 + l;
        int row = q >> 3, sk = q & 7;
        const __hip_bfloat16* g = A + (((size_t)(bm + row)) << 8) + k0 + sk*8;
        GLOAD_LDS16(g, As + (w*256 + i*64)*8);
    }
    #pragma unroll
    for (int i = 0; i < 2; ++i) {
        int q = w*128 + i*64 + l;
        int row = q >> 3, sk = q & 7;
        const __hip_bfloat16* g = Bt + (((size_t)(bn + row)) << 8) + k0 + sk*8;
        GLOAD_LDS16(g, Bs + (w*128 + i*64)*8);
    }
}

template <int OUT_BF16, int NBOUND>
__global__ void mgemm_kernel(const __hip_bfloat16* __restrict__ A,
                             const __hip_bfloat16* __restrict__ Bt,
                             const float* __restrict__ bias,
                             void* __restrict__ Cout, int N, int ldc) {
    __shared__ __bf16 smem[24576];
    int tid = threadIdx.x;
    int w = tid >> 6, l = tid & 63;
    int bn = blockIdx.x * 64;
    int bm = blockIdx.y * 128;
    __bf16* Asb[2] = { smem,        smem + 12288 };
    __bf16* Bsb[2] = { smem + 8192, smem + 20480 };
    f32x4 acc[2][4];
    #pragma unroll
    for (int m = 0; m < 2; ++m)
        #pragma unroll
        for (int n = 0; n < 4; ++n)
            acc[m][n] = (f32x4){0.f, 0.f, 0.f, 0.f};

    stage_tile(A, Bt, Asb[0], Bsb[0], bm, bn, 0, w, l);
    __syncthreads();
    int lr = l & 15, kg = l >> 4;
    #pragma unroll
    for (int t = 0; t < 4; ++t) {
        int cur = t & 1;
        if (t < 3) stage_tile(A, Bt, Asb[cur^1], Bsb[cur^1], bm, bn, (t+1)*64, w, l);
        const __bf16* Ab = Asb[cur];
        const __bf16* Bb = Bsb[cur];
        bf16x8 af[2][2], bfr[4][2];
        #pragma unroll
        for (int m = 0; m < 2; ++m)
            #pragma unroll
            for (int u = 0; u < 2; ++u)
                af[m][u] = *(const bf16x8*)&Ab[(w*32 + m*16 + lr)*64 + u*32 + kg*8];
        #pragma unroll
        for (int n = 0; n < 4; ++n)
            #pragma unroll
            for (int u = 0; u < 2; ++u)
                bfr[n][u] = *(const bf16x8*)&Bb[(n*16 + lr)*64 + u*32 + kg*8];
        #pragma unroll
        for (int u = 0; u < 2; ++u)
            #pragma unroll
            for (int m = 0; m < 2; ++m)
                #pragma unroll
                for (int n = 0; n < 4; ++n)
                    acc[m][n] = __builtin_amdgcn_mfma_f32_16x16x32_bf16(af[m][u], bfr[n][u], acc[m][n], 0, 0, 0);
        __syncthreads();
    }
    int orow = bm + w*32 + kg*4;
    #pragma unroll
    for (int n = 0; n < 4; ++n) {
        int ccol = bn + n*16 + lr;
        if (NBOUND && ccol >= N) continue;
        float bv = bias[ccol];
        #pragma unroll
        for (int m = 0; m < 2; ++m) {
            #pragma unroll
            for (int j = 0; j < 4; ++j) {
                size_t o = (size_t)(orow + m*16 + j) * ldc + ccol;
                float v = acc[m][n][j] + bv;
                if (OUT_BF16) ((__hip_bfloat16*)Cout)[o] = __float2bfloat16(v);
                else          ((float*)Cout)[o] = v;
            }
        }
    }
}

// ---------------------------------------------------------------------------
// K4: in-place softmax over P=9 per (pixel, group)
__global__ void softmax_kernel(float* __restrict__ m) {
    int idx = blockIdx.x * blockDim.x + threadIdx.x;
    float* p = m + (size_t)idx * 9;
    float v[9];
    float mx = -1e30f;
    #pragma unroll
    for (int i = 0; i < 9; ++i) { v[i] = p[i]; mx = fmaxf(mx, v[i]); }
    float s = 0.0f;
    #pragma unroll
    for (int i = 0; i < 9; ++i) { v[i] = expf(v[i] - mx); s += v[i]; }
    float r = 1.0f / s;
    #pragma unroll
    for (int i = 0; i < 9; ++i) p[i] = v[i] * r;
}

// ---------------------------------------------------------------------------
// K5: DCNv3 core. xproj bf16 NHWC, off/msk fp32 -> y bf16.
__device__ __forceinline__ void bfu2(unsigned a, float& lo, float& hi) {
    union { unsigned u; float f; } t0, t1;
    t0.u = a << 16; t1.u = a & 0xffff0000u;
    lo = t0.f; hi = t1.f;
}

__global__ void dcn_kernel(const __hip_bfloat16* __restrict__ xproj,
                           const float* __restrict__ off,
                           const float* __restrict__ msk,
                           __hip_bfloat16* __restrict__ y) {
    __shared__ float4 wLds[1152];   // 8 px * 144 (g*9+p)
    __shared__ int4   oLds[1152];
    int pix0 = blockIdx.x * 8;
    // ---- phase 1: weights + corner offsets ----
    for (int tau = threadIdx.x; tau < 1152; tau += 256) {
        int px = tau / 144;
        int gp = tau - px * 144;
        int g  = gp / 9, p = gp - g * 9;
        int pix = pix0 + px;
        int wo = pix & 63, ho = (pix >> 6) & 63;
        const float* ob = off + (size_t)pix * 288 + g * 18 + p * 2;
        float offx = ob[0];
        float offy = ob[1];
        float m = msk[(size_t)pix * 144 + gp];
        int dx = p / 3 - 1;
        int dy = p - (p / 3) * 3 - 1;
        float fx = (float)(wo + dx) + offx;
        float fy = (float)(ho + dy) + offy;
        float x0f = floorf(fx), y0f = floorf(fy);
        int x0 = (int)x0f, y0 = (int)y0f;
        int x1 = x0 + 1, y1 = y0 + 1;
        float wx1 = fx - x0f, wx0 = 1.0f - wx1;
        float wy1 = fy - y0f, wy0 = 1.0f - wy1;
        float vx0 = (x0 >= 0 && x0 < WW) ? 1.0f : 0.0f;
        float vx1 = (x1 >= 0 && x1 < WW) ? 1.0f : 0.0f;
        float vy0 = (y0 >= 0 && y0 < HH) ? 1.0f : 0.0f;
        float vy1 = (y1 >= 0 && y1 < HH) ? 1.0f : 0.0f;
        int x0c = min(max(x0, 0), WW - 1), x1c = min(max(x1, 0), WW - 1);
        int y0c = min(max(y0, 0), HH - 1), y1c = min(max(y1, 0), HH - 1);
        wLds[tau] = make_float4(m * wy0 * wx0 * vy0 * vx0,
                                m * wy0 * wx1 * vy0 * vx1,
                                m * wy1 * wx0 * vy1 * vx0,
                                m * wy1 * wx1 * vy1 * vx1);
        oLds[tau] = make_int4((y0c * WW + x0c) << 8, (y0c * WW + x1c) << 8,
                              (y1c * WW + x0c) << 8, (y1c * WW + x1c) << 8);
    }
    __syncthreads();
    // ---- phase 2: gather 8 channels per thread ----
    int t  = threadIdx.x;
    int px = t >> 5;
    int l  = t & 31;
    int g  = l >> 1;
    int ch = g * 16 + (l & 1) * 8;
    int pix = pix0 + px;
    int n = pix >> 12;
    const __hip_bfloat16* xb = xproj + ((size_t)n << 20) + ch;
    float a0=0,a1=0,a2=0,a3=0,a4=0,a5=0,a6=0,a7=0;
    const float4* wp = &wLds[px * 144 + g * 9];
    const int4*  op = &oLds[px * 144 + g * 9];
    #pragma unroll
    for (int p = 0; p < 9; ++p) {
        float4 w = wp[p];
        int4  o = op[p];
        {
            uint4 u = *(const uint4*)(xb + o.x);
            float b0,b1,b2,b3,b4,b5,b6,b7;
            bfu2(u.x,b0,b1); bfu2(u.y,b2,b3); bfu2(u.z,b4,b5); bfu2(u.w,b6,b7);
            a0 += w.x*b0; a1 += w.x*b1; a2 += w.x*b2; a3 += w.x*b3;
            a4 += w.x*b4; a5 += w.x*b5; a6 += w.x*b6; a7 += w.x*b7;
        }
        {
            uint4 u = *(const uint4*)(xb + o.y);
            float b0,b1,b2,b3,b4,b5,b6,b7;
            bfu2(u.x,b0,b1); bfu2(u.y,b2,b3); bfu2(u.z,b4,b5); bfu2(u.w,b6,b7);
            a0 += w.y*b0; a1 += w.y*b1; a2 += w.y*b2; a3 += w.y*b3;
            a4 += w.y*b4; a5 += w.y*b5; a6 += w.y*b6; a7 += w.y*b7;
        }
        {
            uint4 u = *(const uint4*)(xb + o.z);
            float b0,b1,b2,b3,b4,b5,b6,b7;
            bfu2(u.x,b0,b1); bfu2(u.y,b2,b3); bfu2(u.z,b4,b5); bfu2(u.w,b6,b7);
            a0 += w.z*b0; a1 += w.z*b1; a2 += w.z*b2; a3 += w.z*b3;
            a4 += w.z*b4; a5 += w.z*b5; a6 += w.z*b6; a7 += w.z*b7;
        }
        {
            uint4 u = *(const uint4*)(xb + o.w);
            float b0,b1,b2,b3,b4,b5,b6,b7;
            bfu2(u.x,b0,b1); bfu2(u.y,b2,b3); bfu2(u.z,b4,b5); bfu2(u.w,b6,b7);
            a0 += w.w*b0; a1 += w.w*b1; a2 += w.w*b2; a3 += w.w*b3;
            a4 += w.w*b4; a5 += w.w*b5; a6 += w.w*b6; a7 += w.w*b7;
        }
    }
    union { __hip_bfloat16 h[8]; uint4 u; } ov;
    ov.h[0]=__float2bfloat16(a0); ov.h[1]=__float2bfloat16(a1);
    ov.h[2]=__float2bfloat16(a2); ov.h[3]=__float2bfloat16(a3);
    ov.h[4]=__float2bfloat16(a4); ov.h[5]=__float2bfloat16(a5);
    ov.h[6]=__float2bfloat16(a6); ov.h[7]=__float2bfloat16(a7);
    *(uint4*)(y + (size_t)pix * CC + ch) = ov.u;
}

// ---------------------------------------------------------------------------
// K6: out[n,d,h,w] = x[n,d,h,w] * attn[pix, d]
__global__ void finmul_kernel(const float* __restrict__ x, const float* __restrict__ attn,
                              float* __restrict__ out) {
    __shared__ float t[16][17];
    int pix0 = blockIdx.x * 16;
    int d0   = blockIdx.y * 16;
    int li = threadIdx.x & 15;
    int lj = threadIdx.x >> 4;
    t[lj][li] = attn[(size_t)(pix0 + lj)*CC + d0 + li];
    __syncthreads();
    int pix = pix0 + li;
    int wo = pix & 63;
    int ho = (pix >> 6) & 63;
    int n  = pix >> 12;
    int d = d0 + lj;
    size_t oidx = (((size_t)n*CC + d)*HH + ho)*WW + wo;
    out[oidx] = x[oidx] * t[li][lj];
}

// ---------------------------------------------------------------------------
extern "C" void kernel_launch(void* const* d_in, const int* in_sizes, int n_in,
                              void* d_out, int out_size, void* d_ws, size_t ws_size,
                              hipStream_t stream) {
    const float* x      = (const float*)d_in[0];
    const float* conv0w = (const float*)d_in[1];
    const float* conv0b = (const float*)d_in[2];
    const float* dww    = (const float*)d_in[3];
    const float* dwb    = (const float*)d_in[4];
    const float* lng    = (const float*)d_in[5];
    const float* lnb    = (const float*)d_in[6];
    const float* offw   = (const float*)d_in[7];
    const float* offb   = (const float*)d_in[8];
    const float* mskw   = (const float*)d_in[9];
    const float* mskb   = (const float*)d_in[10];
    const float* inw    = (const float*)d_in[11];
    const float* inb    = (const float*)d_in[12];
    const float* outpw  = (const float*)d_in[13];
    const float* outpb  = (const float*)d_in[14];
    const float* pww    = (const float*)d_in[15];
    const float* pwb    = (const float*)d_in[16];

    float* ws   = (float*)d_ws;
    float* off  = ws;                          // 9,437,184 floats
    float* msk  = ws + 9437184;                // 4,718,592
    float* inpf = ws + 14155776;               // 8,388,608 (attn aliases)
    float* attn = inpf;
    __hip_bfloat16* bfb    = (__hip_bfloat16*)(ws + 22544384);
    __hip_bfloat16* inp_bf = bfb;              // 8,388,608 elems (y_bf aliases)
    __hip_bfloat16* y_bf   = inp_bf;
    __hip_bfloat16* x1_bf  = bfb + 8388608;    // (xpj_bf, z_bf alias)
    __hip_bfloat16* xpj_bf = x1_bf;
    __hip_bfloat16* z_bf   = x1_bf;
    __hip_bfloat16* bt_in   = bfb + 16777216;  // 256*256
    __hip_bfloat16* bt_off  = bt_in  + 65536;  // 320*256
    __hip_bfloat16* bt_msk  = bt_off + 81920;  // 192*256
    __hip_bfloat16* bt_outp = bt_msk + 49152;  // 256*256
    __hip_bfloat16* bt_pw   = bt_outp + 65536; // 256*256
    float* out = (float*)d_out;

    // weight conversion
    wcvt_t_kernel<<<256, 256, 0, stream>>>(inw,   bt_in,   256);
    wcvt_t_kernel<<<320, 256, 0, stream>>>(offw,  bt_off,  288);
    wcvt_t_kernel<<<192, 256, 0, stream>>>(mskw,  bt_msk,  144);
    wcvt_t_kernel<<<256, 256, 0, stream>>>(outpw, bt_outp, 256);
    wcvt_n_kernel<<<256, 256, 0, stream>>>(pww,   bt_pw);

    // 1. conv0 5x5 dw -> inpf (fp32) + inp_bf  (full-width strip version)
    conv0_kernel<<<dim3(8, 16, BB), 256, 0, stream>>>(x, conv0w, conv0b, inpf, inp_bf);
    // 2. dw3x3 + LN + GELU -> x1_bf
    dwln_kernel<<<NPIX, 256, 0, stream>>>(inpf, dww, dwb, lng, lnb, x1_bf);
    // 3. offset = x1 @ off_w + off_b (fp32)
    mgemm_kernel<0,1><<<dim3(5, 256), 256, 0, stream>>>(x1_bf, bt_off, offb, off, 288, 288);
    // 4. mask logits = x1 @ msk_w + msk_b (fp32)
    mgemm_kernel<0,1><<<dim3(3, 256), 256, 0, stream>>>(x1_bf, bt_msk, mskb, msk, 144, 144);
    // 5. softmax
    softmax_kernel<<<(NPIX*GG)/256, 256, 0, stream>>>(msk);
    // 6. xproj = inp @ in_w + in_b -> bf16 (overwrites x1_bf region; x1 dead)
    mgemm_kernel<1,0><<<dim3(4, 256), 256, 0, stream>>>(inp_bf, bt_in, inb, xpj_bf, 256, 256);
    // 7. DCN core -> y_bf (overwrites inp_bf region; inp dead)
    dcn_kernel<<<NPIX/8, 256, 0, stream>>>(xpj_bf, off, msk, y_bf);
    // 8. z = y @ outp_w + outp_b -> bf16 (overwrites xpj region; xpj dead)
    mgemm_kernel<1,0><<<dim3(4, 256), 256, 0, stream>>>(y_bf, bt_outp, outpb, z_bf, 256, 256);
    // 9. attn = z @ pw_w^T + pw_b -> fp32 (overwrites inpf; inpf dead)
    mgemm_kernel<0,0><<<dim3(4, 256), 256, 0, stream>>>(z_bf, bt_pw, pwb, attn, 256, 256);
    // 10. out = x * attn (NCHW)
    finmul_kernel<<<dim3(NPIX/16, 16), 256, 0, stream>>>(x, attn, out);
}

// Round 6
// 226.808 us; speedup vs baseline: 8.9932x; 1.1607x over previous
//
#include <hip/hip_runtime.h>
#include <hip/hip_bf16.h>
#include <math.h>

// Problem constants
#define BB 8
#define CC 256
#define HH 64
#define WW 64
#define GG 16
#define GCH 16
#define PP 9
#define NPIX (BB*HH*WW)   // 32768

typedef __attribute__((ext_vector_type(4))) float f32x4;
typedef __bf16 bf16x8 __attribute__((ext_vector_type(8)));

#define GLOAD_LDS16(g, l) __builtin_amdgcn_global_load_lds( \
    (const __attribute__((address_space(1))) unsigned int*)(g), \
    (__attribute__((address_space(3))) unsigned int*)(l), 16, 0, 0)

// ---------------------------------------------------------------------------
// K1 v3: 5x5 depthwise conv, pad 2. x: NCHW fp32 -> out NHWC fp32 + bf16.
#define C0PLANE 817   // 12*68 + 1
__global__ void conv0_kernel(const float* __restrict__ x, const float* __restrict__ w,
                             const float* __restrict__ b, float* __restrict__ out,
                             __hip_bfloat16* __restrict__ out_bf) {
    __shared__ float sx[16 * C0PLANE];   // 52288 B
    int t  = threadIdx.x;
    int st = blockIdx.x;                 // row strip 0..7
    int cg = blockIdx.y;                 // channel group
    int n  = blockIdx.z;
    int h0 = st * 8;
    int c0 = cg * 16;

    #pragma unroll
    for (int i = 0; i < 12; ++i) {
        int task = i * 256 + t;
        int lane = task & 15;
        int pair = task >> 4;
        int c    = pair / 12;
        int row  = pair - c * 12;
        int gy   = h0 - 2 + row;
        float4 v = make_float4(0.f, 0.f, 0.f, 0.f);
        if (gy >= 0 && gy < HH)
            v = *(const float4*)(x + (((size_t)(n * CC + c0 + c)) * HH + gy) * WW + lane * 4);
        *(float4*)&sx[c * C0PLANE + row * 68 + 2 + lane * 4] = v;
    }
    if (t < 192) {
        int c = t / 12, row = t - (t / 12) * 12;
        float* p = &sx[c * C0PLANE + row * 68];
        p[0] = 0.f; p[1] = 0.f; p[66] = 0.f; p[67] = 0.f;
    }
    __syncthreads();

    int c = t & 15;
    int s = t >> 4;
    float wreg[25];
    const float* wp = w + (c0 + c) * 25;
    #pragma unroll
    for (int i = 0; i < 25; ++i) wreg[i] = wp[i];
    float bias = b[c0 + c];
    const float* cp = &sx[c * C0PLANE + s * 4];

    float win[5][8];
    #pragma unroll
    for (int rr = 0; rr < 4; ++rr)
        #pragma unroll
        for (int j = 0; j < 8; ++j) win[rr][j] = cp[rr * 68 + j];

    #pragma unroll
    for (int r = 0; r < 8; ++r) {
        #pragma unroll
        for (int j = 0; j < 8; ++j) win[(r + 4) % 5][j] = cp[(r + 4) * 68 + j];
        float a0 = bias, a1 = bias, a2 = bias, a3 = bias;
        #pragma unroll
        for (int dy = 0; dy < 5; ++dy) {
            const float* wr = &wreg[dy * 5];
            const float* wd = win[(r + dy) % 5];
            #pragma unroll
            for (int dx = 0; dx < 5; ++dx) {
                float wv = wr[dx];
                a0 += wd[0 + dx] * wv;
                a1 += wd[1 + dx] * wv;
                a2 += wd[2 + dx] * wv;
                a3 += wd[3 + dx] * wv;
            }
        }
        size_t pixb = ((size_t)n * 4096 + (h0 + r) * 64 + s * 4) << 8;
        out[pixb + c0 + c]         = a0;
        out[pixb + 256 + c0 + c]   = a1;
        out[pixb + 512 + c0 + c]   = a2;
        out[pixb + 768 + c0 + c]   = a3;
        out_bf[pixb + c0 + c]       = __float2bfloat16(a0);
        out_bf[pixb + 256 + c0 + c] = __float2bfloat16(a1);
        out_bf[pixb + 512 + c0 + c] = __float2bfloat16(a2);
        out_bf[pixb + 768 + c0 + c] = __float2bfloat16(a3);
    }
}

// ---------------------------------------------------------------------------
// K2 v2: 3x3 depthwise conv NHWC + LayerNorm(C) + exact GELU -> x1 (bf16)
// Block = 256 thr (= channels). Tile = 8 consecutive pixels of one row.
// Halo 3 rows x 10 cols x 256 ch staged in LDS via coalesced float4 loads.
__global__ void dwln_kernel(const float* __restrict__ inp, const float* __restrict__ dww,
                            const float* __restrict__ dwb, const float* __restrict__ lng,
                            const float* __restrict__ lnb, __hip_bfloat16* __restrict__ x1) {
    __shared__ float sx[3 * 10 * 256];   // 30720 B
    __shared__ float ls1[8][4], ls2[8][4];
    int t  = threadIdx.x;
    int x0 = blockIdx.x * 8;
    int h  = blockIdx.y;
    int n  = blockIdx.z;

    // ---- stage halo: 30 (r,xx) sites x 256 ch, float4-coalesced ----
    #pragma unroll
    for (int i = 0; i < 8; ++i) {
        int task = i * 256 + t;          // 0..2047, need 1920
        if (task < 1920) {
            int c4  = task & 63;
            int rem = task >> 6;          // 0..29
            int r   = rem / 10;
            int xx  = rem - r * 10;
            int gy = h + r - 1, gx = x0 + xx - 1;
            float4 v = make_float4(0.f, 0.f, 0.f, 0.f);
            if (gy >= 0 && gy < HH && gx >= 0 && gx < WW)
                v = *(const float4*)(inp + (((size_t)(n * HH + gy)) * WW + gx) * CC + c4 * 4);
            *(float4*)&sx[(r * 10 + xx) * 256 + c4 * 4] = v;
        }
    }
    __syncthreads();

    // ---- conv 3x3: thread = channel, 8 pixels ----
    int c = t;
    float wr[9];
    #pragma unroll
    for (int i = 0; i < 9; ++i) wr[i] = dww[c * 9 + i];
    float bias = dwb[c];
    float a[8];
    #pragma unroll
    for (int px = 0; px < 8; ++px) {
        float acc = bias;
        #pragma unroll
        for (int dy = 0; dy < 3; ++dy)
            #pragma unroll
            for (int dx = 0; dx < 3; ++dx)
                acc += sx[(dy * 10 + px + dx) * 256 + c] * wr[dy * 3 + dx];
        a[px] = acc;
    }

    // ---- LN reductions: all 8 pixels, one barrier ----
    int wid = t >> 6, lane = t & 63;
    #pragma unroll
    for (int px = 0; px < 8; ++px) {
        float s1 = a[px], s2 = a[px] * a[px];
        #pragma unroll
        for (int o = 1; o < 64; o <<= 1) {
            s1 += __shfl_xor(s1, o);
            s2 += __shfl_xor(s2, o);
        }
        if (lane == 0) { ls1[px][wid] = s1; ls2[px][wid] = s2; }
    }
    __syncthreads();

    float gam = lng[c], bet = lnb[c];
    #pragma unroll
    for (int px = 0; px < 8; ++px) {
        float t1 = ls1[px][0] + ls1[px][1] + ls1[px][2] + ls1[px][3];
        float t2 = ls2[px][0] + ls2[px][1] + ls2[px][2] + ls2[px][3];
        float mu  = t1 * (1.0f/256.0f);
        float var = t2 * (1.0f/256.0f) - mu * mu;
        float rr  = rsqrtf(var + 1e-5f);
        float v = (a[px] - mu) * rr * gam + bet;
        float g = 0.5f * v * (1.0f + erff(v * 0.70710678118654752440f));
        x1[(((size_t)(n * HH + h)) * WW + x0 + px) * CC + c] = __float2bfloat16(g);
    }
}

// ---------------------------------------------------------------------------
// Weight conversion: W[K=256][N] fp32 -> Bt[n][k] bf16, rows >= N zero-filled
__global__ void wcvt_t_kernel(const float* __restrict__ W, __hip_bfloat16* __restrict__ Bt, int N) {
    int idx = blockIdx.x * 256 + threadIdx.x;
    int n = idx >> 8, k = idx & 255;
    float v = (n < N) ? W[k * N + n] : 0.0f;
    Bt[idx] = __float2bfloat16(v);
}
__global__ void wcvt_n_kernel(const float* __restrict__ W, __hip_bfloat16* __restrict__ Bt) {
    int idx = blockIdx.x * 256 + threadIdx.x;
    Bt[idx] = __float2bfloat16(W[idx]);
}

// ---------------------------------------------------------------------------
// K3: bf16 MFMA GEMM. A[M,256] bf16, Bt[Npad,256] bf16 (pre-transposed),
// C[M,N] (fp32 or bf16) row stride ldc. Tile 128x64, 4 waves, BK=64, dbuf.
__device__ __forceinline__ void stage_tile(const __hip_bfloat16* __restrict__ A,
                                           const __hip_bfloat16* __restrict__ Bt,
                                           __bf16* As, __bf16* Bs,
                                           int bm, int bn, int k0, int w, int l) {
    #pragma unroll
    for (int i = 0; i < 4; ++i) {
        int q = w*256 + i*64 + l;
        int row = q >> 3, sk = q & 7;
        const __hip_bfloat16* g = A + (((size_t)(bm + row)) << 8) + k0 + sk*8;
        GLOAD_LDS16(g, As + (w*256 + i*64)*8);
    }
    #pragma unroll
    for (int i = 0; i < 2; ++i) {
        int q = w*128 + i*64 + l;
        int row = q >> 3, sk = q & 7;
        const __hip_bfloat16* g = Bt + (((size_t)(bn + row)) << 8) + k0 + sk*8;
        GLOAD_LDS16(g, Bs + (w*128 + i*64)*8);
    }
}

template <int OUT_BF16, int NBOUND>
__global__ void mgemm_kernel(const __hip_bfloat16* __restrict__ A,
                             const __hip_bfloat16* __restrict__ Bt,
                             const float* __restrict__ bias,
                             void* __restrict__ Cout, int N, int ldc) {
    __shared__ __bf16 smem[24576];
    int tid = threadIdx.x;
    int w = tid >> 6, l = tid & 63;
    int bn = blockIdx.x * 64;
    int bm = blockIdx.y * 128;
    __bf16* Asb[2] = { smem,        smem + 12288 };
    __bf16* Bsb[2] = { smem + 8192, smem + 20480 };
    f32x4 acc[2][4];
    #pragma unroll
    for (int m = 0; m < 2; ++m)
        #pragma unroll
        for (int n = 0; n < 4; ++n)
            acc[m][n] = (f32x4){0.f, 0.f, 0.f, 0.f};

    stage_tile(A, Bt, Asb[0], Bsb[0], bm, bn, 0, w, l);
    __syncthreads();
    int lr = l & 15, kg = l >> 4;
    #pragma unroll
    for (int t = 0; t < 4; ++t) {
        int cur = t & 1;
        if (t < 3) stage_tile(A, Bt, Asb[cur^1], Bsb[cur^1], bm, bn, (t+1)*64, w, l);
        const __bf16* Ab = Asb[cur];
        const __bf16* Bb = Bsb[cur];
        bf16x8 af[2][2], bfr[4][2];
        #pragma unroll
        for (int m = 0; m < 2; ++m)
            #pragma unroll
            for (int u = 0; u < 2; ++u)
                af[m][u] = *(const bf16x8*)&Ab[(w*32 + m*16 + lr)*64 + u*32 + kg*8];
        #pragma unroll
        for (int n = 0; n < 4; ++n)
            #pragma unroll
            for (int u = 0; u < 2; ++u)
                bfr[n][u] = *(const bf16x8*)&Bb[(n*16 + lr)*64 + u*32 + kg*8];
        #pragma unroll
        for (int u = 0; u < 2; ++u)
            #pragma unroll
            for (int m = 0; m < 2; ++m)
                #pragma unroll
                for (int n = 0; n < 4; ++n)
                    acc[m][n] = __builtin_amdgcn_mfma_f32_16x16x32_bf16(af[m][u], bfr[n][u], acc[m][n], 0, 0, 0);
        __syncthreads();
    }
    int orow = bm + w*32 + kg*4;
    #pragma unroll
    for (int n = 0; n < 4; ++n) {
        int ccol = bn + n*16 + lr;
        if (NBOUND && ccol >= N) continue;
        float bv = bias[ccol];
        #pragma unroll
        for (int m = 0; m < 2; ++m) {
            #pragma unroll
            for (int j = 0; j < 4; ++j) {
                size_t o = (size_t)(orow + m*16 + j) * ldc + ccol;
                float v = acc[m][n][j] + bv;
                if (OUT_BF16) ((__hip_bfloat16*)Cout)[o] = __float2bfloat16(v);
                else          ((float*)Cout)[o] = v;
            }
        }
    }
}

// ---------------------------------------------------------------------------
// K4: in-place softmax over P=9 per (pixel, group)
__global__ void softmax_kernel(float* __restrict__ m) {
    int idx = blockIdx.x * blockDim.x + threadIdx.x;
    float* p = m + (size_t)idx * 9;
    float v[9];
    float mx = -1e30f;
    #pragma unroll
    for (int i = 0; i < 9; ++i) { v[i] = p[i]; mx = fmaxf(mx, v[i]); }
    float s = 0.0f;
    #pragma unroll
    for (int i = 0; i < 9; ++i) { v[i] = expf(v[i] - mx); s += v[i]; }
    float r = 1.0f / s;
    #pragma unroll
    for (int i = 0; i < 9; ++i) p[i] = v[i] * r;
}

// ---------------------------------------------------------------------------
// K5: DCNv3 core. xproj bf16 NHWC, off/msk fp32 -> y bf16.
__device__ __forceinline__ void bfu2(unsigned a, float& lo, float& hi) {
    union { unsigned u; float f; } t0, t1;
    t0.u = a << 16; t1.u = a & 0xffff0000u;
    lo = t0.f; hi = t1.f;
}

__global__ void dcn_kernel(const __hip_bfloat16* __restrict__ xproj,
                           const float* __restrict__ off,
                           const float* __restrict__ msk,
                           __hip_bfloat16* __restrict__ y) {
    __shared__ float4 wLds[1152];   // 8 px * 144 (g*9+p)
    __shared__ int4   oLds[1152];
    int pix0 = blockIdx.x * 8;
    for (int tau = threadIdx.x; tau < 1152; tau += 256) {
        int px = tau / 144;
        int gp = tau - px * 144;
        int g  = gp / 9, p = gp - g * 9;
        int pix = pix0 + px;
        int wo = pix & 63, ho = (pix >> 6) & 63;
        const float* ob = off + (size_t)pix * 288 + g * 18 + p * 2;
        float offx = ob[0];
        float offy = ob[1];
        float m = msk[(size_t)pix * 144 + gp];
        int dx = p / 3 - 1;
        int dy = p - (p / 3) * 3 - 1;
        float fx = (float)(wo + dx) + offx;
        float fy = (float)(ho + dy) + offy;
        float x0f = floorf(fx), y0f = floorf(fy);
        int x0 = (int)x0f, y0 = (int)y0f;
        int x1 = x0 + 1, y1 = y0 + 1;
        float wx1 = fx - x0f, wx0 = 1.0f - wx1;
        float wy1 = fy - y0f, wy0 = 1.0f - wy1;
        float vx0 = (x0 >= 0 && x0 < WW) ? 1.0f : 0.0f;
        float vx1 = (x1 >= 0 && x1 < WW) ? 1.0f : 0.0f;
        float vy0 = (y0 >= 0 && y0 < HH) ? 1.0f : 0.0f;
        float vy1 = (y1 >= 0 && y1 < HH) ? 1.0f : 0.0f;
        int x0c = min(max(x0, 0), WW - 1), x1c = min(max(x1, 0), WW - 1);
        int y0c = min(max(y0, 0), HH - 1), y1c = min(max(y1, 0), HH - 1);
        wLds[tau] = make_float4(m * wy0 * wx0 * vy0 * vx0,
                                m * wy0 * wx1 * vy0 * vx1,
                                m * wy1 * wx0 * vy1 * vx0,
                                m * wy1 * wx1 * vy1 * vx1);
        oLds[tau] = make_int4((y0c * WW + x0c) << 8, (y0c * WW + x1c) << 8,
                              (y1c * WW + x0c) << 8, (y1c * WW + x1c) << 8);
    }
    __syncthreads();
    int t  = threadIdx.x;
    int px = t >> 5;
    int l  = t & 31;
    int g  = l >> 1;
    int ch = g * 16 + (l & 1) * 8;
    int pix = pix0 + px;
    int n = pix >> 12;
    const __hip_bfloat16* xb = xproj + ((size_t)n << 20) + ch;
    float a0=0,a1=0,a2=0,a3=0,a4=0,a5=0,a6=0,a7=0;
    const float4* wp = &wLds[px * 144 + g * 9];
    const int4*  op = &oLds[px * 144 + g * 9];
    #pragma unroll
    for (int p = 0; p < 9; ++p) {
        float4 w = wp[p];
        int4  o = op[p];
        {
            uint4 u = *(const uint4*)(xb + o.x);
            float b0,b1,b2,b3,b4,b5,b6,b7;
            bfu2(u.x,b0,b1); bfu2(u.y,b2,b3); bfu2(u.z,b4,b5); bfu2(u.w,b6,b7);
            a0 += w.x*b0; a1 += w.x*b1; a2 += w.x*b2; a3 += w.x*b3;
            a4 += w.x*b4; a5 += w.x*b5; a6 += w.x*b6; a7 += w.x*b7;
        }
        {
            uint4 u = *(const uint4*)(xb + o.y);
            float b0,b1,b2,b3,b4,b5,b6,b7;
            bfu2(u.x,b0,b1); bfu2(u.y,b2,b3); bfu2(u.z,b4,b5); bfu2(u.w,b6,b7);
            a0 += w.y*b0; a1 += w.y*b1; a2 += w.y*b2; a3 += w.y*b3;
            a4 += w.y*b4; a5 += w.y*b5; a6 += w.y*b6; a7 += w.y*b7;
        }
        {
            uint4 u = *(const uint4*)(xb + o.z);
            float b0,b1,b2,b3,b4,b5,b6,b7;
            bfu2(u.x,b0,b1); bfu2(u.y,b2,b3); bfu2(u.z,b4,b5); bfu2(u.w,b6,b7);
            a0 += w.z*b0; a1 += w.z*b1; a2 += w.z*b2; a3 += w.z*b3;
            a4 += w.z*b4; a5 += w.z*b5; a6 += w.z*b6; a7 += w.z*b7;
        }
        {
            uint4 u = *(const uint4*)(xb + o.w);
            float b0,b1,b2,b3,b4,b5,b6,b7;
            bfu2(u.x,b0,b1); bfu2(u.y,b2,b3); bfu2(u.z,b4,b5); bfu2(u.w,b6,b7);
            a0 += w.w*b0; a1 += w.w*b1; a2 += w.w*b2; a3 += w.w*b3;
            a4 += w.w*b4; a5 += w.w*b5; a6 += w.w*b6; a7 += w.w*b7;
        }
    }
    union { __hip_bfloat16 h[8]; uint4 u; } ov;
    ov.h[0]=__float2bfloat16(a0); ov.h[1]=__float2bfloat16(a1);
    ov.h[2]=__float2bfloat16(a2); ov.h[3]=__float2bfloat16(a3);
    ov.h[4]=__float2bfloat16(a4); ov.h[5]=__float2bfloat16(a5);
    ov.h[6]=__float2bfloat16(a6); ov.h[7]=__float2bfloat16(a7);
    *(uint4*)(y + (size_t)pix * CC + ch) = ov.u;
}

// ---------------------------------------------------------------------------
// K6: out[n,d,h,w] = x[n,d,h,w] * attn[pix, d]
__global__ void finmul_kernel(const float* __restrict__ x, const float* __restrict__ attn,
                              float* __restrict__ out) {
    __shared__ float t[16][17];
    int pix0 = blockIdx.x * 16;
    int d0   = blockIdx.y * 16;
    int li = threadIdx.x & 15;
    int lj = threadIdx.x >> 4;
    t[lj][li] = attn[(size_t)(pix0 + lj)*CC + d0 + li];
    __syncthreads();
    int pix = pix0 + li;
    int wo = pix & 63;
    int ho = (pix >> 6) & 63;
    int n  = pix >> 12;
    int d = d0 + lj;
    size_t oidx = (((size_t)n*CC + d)*HH + ho)*WW + wo;
    out[oidx] = x[oidx] * t[li][lj];
}

// ---------------------------------------------------------------------------
extern "C" void kernel_launch(void* const* d_in, const int* in_sizes, int n_in,
                              void* d_out, int out_size, void* d_ws, size_t ws_size,
                              hipStream_t stream) {
    const float* x      = (const float*)d_in[0];
    const float* conv0w = (const float*)d_in[1];
    const float* conv0b = (const float*)d_in[2];
    const float* dww    = (const float*)d_in[3];
    const float* dwb    = (const float*)d_in[4];
    const float* lng    = (const float*)d_in[5];
    const float* lnb    = (const float*)d_in[6];
    const float* offw   = (const float*)d_in[7];
    const float* offb   = (const float*)d_in[8];
    const float* mskw   = (const float*)d_in[9];
    const float* mskb   = (const float*)d_in[10];
    const float* inw    = (const float*)d_in[11];
    const float* inb    = (const float*)d_in[12];
    const float* outpw  = (const float*)d_in[13];
    const float* outpb  = (const float*)d_in[14];
    const float* pww    = (const float*)d_in[15];
    const float* pwb    = (const float*)d_in[16];

    float* ws   = (float*)d_ws;
    float* off  = ws;                          // 9,437,184 floats
    float* msk  = ws + 9437184;                // 4,718,592
    float* inpf = ws + 14155776;               // 8,388,608 (attn aliases)
    float* attn = inpf;
    __hip_bfloat16* bfb    = (__hip_bfloat16*)(ws + 22544384);
    __hip_bfloat16* inp_bf = bfb;              // 8,388,608 elems (y_bf aliases)
    __hip_bfloat16* y_bf   = inp_bf;
    __hip_bfloat16* x1_bf  = bfb + 8388608;    // (xpj_bf, z_bf alias)
    __hip_bfloat16* xpj_bf = x1_bf;
    __hip_bfloat16* z_bf   = x1_bf;
    __hip_bfloat16* bt_in   = bfb + 16777216;  // 256*256
    __hip_bfloat16* bt_off  = bt_in  + 65536;  // 320*256
    __hip_bfloat16* bt_msk  = bt_off + 81920;  // 192*256
    __hip_bfloat16* bt_outp = bt_msk + 49152;  // 256*256
    __hip_bfloat16* bt_pw   = bt_outp + 65536; // 256*256
    float* out = (float*)d_out;

    // weight conversion
    wcvt_t_kernel<<<256, 256, 0, stream>>>(inw,   bt_in,   256);
    wcvt_t_kernel<<<320, 256, 0, stream>>>(offw,  bt_off,  288);
    wcvt_t_kernel<<<192, 256, 0, stream>>>(mskw,  bt_msk,  144);
    wcvt_t_kernel<<<256, 256, 0, stream>>>(outpw, bt_outp, 256);
    wcvt_n_kernel<<<256, 256, 0, stream>>>(pww,   bt_pw);

    // 1. conv0 5x5 dw -> inpf (fp32) + inp_bf
    conv0_kernel<<<dim3(8, 16, BB), 256, 0, stream>>>(x, conv0w, conv0b, inpf, inp_bf);
    // 2. dw3x3 + LN + GELU -> x1_bf  (8-px row-tile version)
    dwln_kernel<<<dim3(8, 64, BB), 256, 0, stream>>>(inpf, dww, dwb, lng, lnb, x1_bf);
    // 3. offset = x1 @ off_w + off_b (fp32)
    mgemm_kernel<0,1><<<dim3(5, 256), 256, 0, stream>>>(x1_bf, bt_off, offb, off, 288, 288);
    // 4. mask logits = x1 @ msk_w + msk_b (fp32)
    mgemm_kernel<0,1><<<dim3(3, 256), 256, 0, stream>>>(x1_bf, bt_msk, mskb, msk, 144, 144);
    // 5. softmax
    softmax_kernel<<<(NPIX*GG)/256, 256, 0, stream>>>(msk);
    // 6. xproj = inp @ in_w + in_b -> bf16
    mgemm_kernel<1,0><<<dim3(4, 256), 256, 0, stream>>>(inp_bf, bt_in, inb, xpj_bf, 256, 256);
    // 7. DCN core -> y_bf
    dcn_kernel<<<NPIX/8, 256, 0, stream>>>(xpj_bf, off, msk, y_bf);
    // 8. z = y @ outp_w + outp_b -> bf16
    mgemm_kernel<1,0><<<dim3(4, 256), 256, 0, stream>>>(y_bf, bt_outp, outpb, z_bf, 256, 256);
    // 9. attn = z @ pw_w^T + pw_b -> fp32
    mgemm_kernel<0,0><<<dim3(4, 256), 256, 0, stream>>>(z_bf, bt_pw, pwb, attn, 256, 256);
    // 10. out = x * attn (NCHW)
    finmul_kernel<<<dim3(NPIX/16, 16), 256, 0, stream>>>(x, attn, out);
}